// Round 1
// baseline (984.989 us; speedup 1.0000x reference)
//
#include <hip/hip_runtime.h>
#include <hip/hip_bf16.h>

// ---------------------------------------------------------------------------
// TokenFlowModel block on MI355X (gfx950).
// B=1, S=2048, D=2048, H=16, KVH=8, HD=128, FH=5632, M_=8, N_=256.
// Strategy: convert weights to bf16 W^T once per call; all GEMMs are
// 128x128-tile bf16 MFMA (16x16x32) with f32 accum; flash attention with
// online softmax; epilogue fusion for modulation / silu-mul / residual-add.
// ---------------------------------------------------------------------------

typedef __attribute__((ext_vector_type(8))) short short8;   // 8 x bf16
typedef __attribute__((ext_vector_type(4))) float f32x4;
typedef __attribute__((ext_vector_type(4))) unsigned short u16x4;

#define MFMA_BF16(a, b, c) __builtin_amdgcn_mfma_f32_16x16x32_bf16((a), (b), (c), 0, 0, 0)

__device__ __forceinline__ unsigned short f2b_bits(float f) {
    union { float f; unsigned int u; } cv; cv.f = f;
    unsigned int u = cv.u;
    u += 0x7fffu + ((u >> 16) & 1u);   // round-to-nearest-even
    return (unsigned short)(u >> 16);
}
__device__ __forceinline__ float b2f_bits(unsigned short b) {
    union { float f; unsigned int u; } cv; cv.u = ((unsigned int)b) << 16; return cv.f;
}
__device__ __forceinline__ float silu_f(float x) { return x / (1.0f + __expf(-x)); }

// ---------------------------------------------------------------------------
// Weight transpose + f32->bf16: W[K][N] f32  ->  WT[N][K] bf16
// ---------------------------------------------------------------------------
__global__ __launch_bounds__(256) void transpose_kernel(
    const float* __restrict__ W, unsigned short* __restrict__ WT, int K, int N)
{
    __shared__ float t[64][65];
    const int tid = threadIdx.x;
    const int k0 = blockIdx.y * 64, n0 = blockIdx.x * 64;
    {
        const int row = tid >> 2, cq = (tid & 3) * 16;
        const float* src = W + (size_t)(k0 + row) * N + n0 + cq;
        #pragma unroll
        for (int i = 0; i < 4; i++) {
            float4 v = *(const float4*)(src + i * 4);
            t[row][cq + i * 4 + 0] = v.x;
            t[row][cq + i * 4 + 1] = v.y;
            t[row][cq + i * 4 + 2] = v.z;
            t[row][cq + i * 4 + 3] = v.w;
        }
    }
    __syncthreads();
    {
        const int n = tid >> 2, kq = (tid & 3) * 16;
        short8 v0, v1;
        #pragma unroll
        for (int i = 0; i < 8; i++) {
            v0[i] = (short)f2b_bits(t[kq + i][n]);
            v1[i] = (short)f2b_bits(t[kq + 8 + i][n]);
        }
        unsigned short* dst = WT + (size_t)(n0 + n) * K + k0 + kq;
        *(short8*)(dst) = v0;
        *(short8*)(dst + 8) = v1;
    }
}

// ---------------------------------------------------------------------------
// silu(vec) -> sv   (8 x 2048)
// ---------------------------------------------------------------------------
__global__ void silu_kernel(const float* __restrict__ in, float* __restrict__ outp, int n) {
    int i = blockIdx.x * 256 + threadIdx.x;
    if (i < n) outp[i] = silu_f(in[i]);
}

// ---------------------------------------------------------------------------
// mod[8][6144] = sv[8][2048] @ mod_w[2048][6144] + mod_b
// ---------------------------------------------------------------------------
__global__ __launch_bounds__(256) void mod_gemm_kernel(
    const float* __restrict__ sv, const float* __restrict__ mw,
    const float* __restrict__ mb, float* __restrict__ mod)
{
    __shared__ float svs[2048];
    const int m = blockIdx.y, tid = threadIdx.x;
    const int n = blockIdx.x * 256 + tid;
    for (int i = tid; i < 2048; i += 256) svs[i] = sv[m * 2048 + i];
    __syncthreads();
    float acc = 0.0f;
    #pragma unroll 8
    for (int k = 0; k < 2048; k++) acc += svs[k] * mw[(size_t)k * 6144 + n];
    mod[m * 6144 + n] = acc + mb[n];
}

// ---------------------------------------------------------------------------
// RMSNorm (+ optional AdaLN modulation) -> bf16 row.  One block per row.
// MOD: out = rms(x)*w*(1+scale[g]) + shift[g],  g = row>>8
// ---------------------------------------------------------------------------
template<bool MOD>
__global__ __launch_bounds__(256) void norm_kernel(
    const float* __restrict__ xin, const float* __restrict__ w,
    const float* __restrict__ mod, unsigned short* __restrict__ outp)
{
    const int s = blockIdx.x, tid = threadIdx.x;
    const float* xr = xin + (size_t)s * 2048;
    float4 a4 = *(const float4*)(xr + tid * 8);
    float4 b4 = *(const float4*)(xr + tid * 8 + 4);
    float v[8] = {a4.x, a4.y, a4.z, a4.w, b4.x, b4.y, b4.z, b4.w};
    float ss = 0.0f;
    #pragma unroll
    for (int i = 0; i < 8; i++) ss += v[i] * v[i];
    #pragma unroll
    for (int off = 1; off < 64; off <<= 1) ss += __shfl_xor(ss, off);
    __shared__ float red[4];
    if ((tid & 63) == 0) red[tid >> 6] = ss;
    __syncthreads();
    ss = red[0] + red[1] + red[2] + red[3];
    const float inv = rsqrtf(ss * (1.0f / 2048.0f) + 1e-6f);
    const int g = s >> 8;
    #pragma unroll
    for (int i = 0; i < 8; i++) {
        const int d = tid * 8 + i;
        float y = v[i] * inv * w[d];
        if (MOD) y = y * (1.0f + mod[g * 6144 + 2048 + d]) + mod[g * 6144 + d];
        outp[(size_t)s * 2048 + d] = f2b_bits(y);
    }
}

// ---------------------------------------------------------------------------
// Rope (interleaved pairs). in/out: [S][HEADS][128] bf16. One thread per pair.
// ---------------------------------------------------------------------------
template<int HEADS>
__global__ __launch_bounds__(256) void rope_kernel(
    const unsigned short* __restrict__ in, unsigned short* __restrict__ outp,
    const float* __restrict__ ct, const float* __restrict__ st)
{
    const int idx = blockIdx.x * 256 + threadIdx.x;   // pair index
    const int p = idx & 63;
    const int s = idx / (HEADS * 64);
    const float c = ct[s * 64 + p], sn = st[s * 64 + p];
    const unsigned int pr = *(const unsigned int*)(in + (size_t)idx * 2);
    const float xr = b2f_bits((unsigned short)(pr & 0xffffu));
    const float xi = b2f_bits((unsigned short)(pr >> 16));
    const unsigned int lo = f2b_bits(xr * c - xi * sn);
    const unsigned int hi = f2b_bits(xr * sn + xi * c);
    *(unsigned int*)(outp + (size_t)idx * 2) = lo | (hi << 16);
}

// ---------------------------------------------------------------------------
// Generic bf16 GEMM: C[M][N] = A[M][K](bf16) @ BT[N][K](bf16)^T, f32 accum.
// 128x128 tile, BK=32, 4 waves in 2x2, 4x4 16x16x32 frags per wave.
// Epilogues fuse the surrounding elementwise ops.
// ---------------------------------------------------------------------------
enum { EP_BF16 = 0, EP_VT = 1, EP_XGATE = 2, EP_SILUMUL = 3, EP_ADDOUT = 4 };

template<int EPI>
__global__ __launch_bounds__(256) void gemm_kernel(
    const unsigned short* __restrict__ A, const unsigned short* __restrict__ BT,
    void* __restrict__ outp,
    const float* __restrict__ xin,   // EP_XGATE: residual x
    const float* __restrict__ modp,  // EP_XGATE: mod (gate at +4096)
    const unsigned short* __restrict__ up,  // EP_SILUMUL: u = hn@w1 (bf16)
    int M, int N, int K)
{
    __shared__ unsigned short As[128][40];  // +8 pad: conflict-light b128 reads
    __shared__ unsigned short Bs[128][40];
    const int tid = threadIdx.x;
    const int lane = tid & 63, wave = tid >> 6;
    const int m0 = blockIdx.y * 128, n0 = blockIdx.x * 128;
    const int wr = (wave >> 1) * 64, wc = (wave & 1) * 64;
    const int lr = lane & 15, lg = lane >> 4;
    const int sr = tid >> 2, sc = (tid & 3) * 8;

    f32x4 acc[4][4];
    #pragma unroll
    for (int i = 0; i < 4; i++)
        #pragma unroll
        for (int j = 0; j < 4; j++) acc[i][j] = (f32x4){0.f, 0.f, 0.f, 0.f};

    const unsigned short* Ar0 = A + (size_t)(m0 + sr) * K + sc;
    const unsigned short* Ar1 = A + (size_t)(m0 + sr + 64) * K + sc;
    const unsigned short* Br0 = BT + (size_t)(n0 + sr) * K + sc;
    const unsigned short* Br1 = BT + (size_t)(n0 + sr + 64) * K + sc;

    for (int k0 = 0; k0 < K; k0 += 32) {
        __syncthreads();
        *(short8*)&As[sr][sc]      = *(const short8*)(Ar0 + k0);
        *(short8*)&As[sr + 64][sc] = *(const short8*)(Ar1 + k0);
        *(short8*)&Bs[sr][sc]      = *(const short8*)(Br0 + k0);
        *(short8*)&Bs[sr + 64][sc] = *(const short8*)(Br1 + k0);
        __syncthreads();
        short8 af[4], bfr[4];
        #pragma unroll
        for (int i = 0; i < 4; i++) {
            af[i]  = *(const short8*)&As[wr + i * 16 + lr][8 * lg];
            bfr[i] = *(const short8*)&Bs[wc + i * 16 + lr][8 * lg];
        }
        #pragma unroll
        for (int i = 0; i < 4; i++)
            #pragma unroll
            for (int j = 0; j < 4; j++)
                acc[i][j] = MFMA_BF16(af[i], bfr[j], acc[i][j]);
    }

    // Epilogue. D layout: row = (lane>>4)*4 + reg, col = lane&15 (HW-verified).
    #pragma unroll
    for (int i = 0; i < 4; i++) {
        #pragma unroll
        for (int j = 0; j < 4; j++) {
            const int rb = m0 + wr + i * 16 + lg * 4;
            const int c  = n0 + wc + j * 16 + lr;
            if constexpr (EPI == EP_VT) {
                u16x4 pk;
                #pragma unroll
                for (int r = 0; r < 4; r++) pk[r] = f2b_bits(acc[i][j][r]);
                *(u16x4*)((unsigned short*)outp + (size_t)c * M + rb) = pk;  // vT[c][rb..rb+3]
            } else {
                #pragma unroll
                for (int r = 0; r < 4; r++) {
                    const int row = rb + r;
                    const size_t idx = (size_t)row * N + c;
                    const float v = acc[i][j][r];
                    if constexpr (EPI == EP_BF16) {
                        ((unsigned short*)outp)[idx] = f2b_bits(v);
                    } else if constexpr (EPI == EP_XGATE) {
                        ((float*)outp)[idx] = xin[idx] + modp[(row >> 8) * 6144 + 4096 + c] * v;
                    } else if constexpr (EPI == EP_SILUMUL) {
                        const float uu = b2f_bits(up[idx]);
                        ((unsigned short*)outp)[idx] = f2b_bits(silu_f(uu) * v);
                    } else {  // EP_ADDOUT
                        ((float*)outp)[idx] = ((float*)outp)[idx] + v;
                    }
                }
            }
        }
    }
}

// ---------------------------------------------------------------------------
// Flash attention, causal, GQA (head h uses kv head h>>1).
// Block = (64 q-rows, 1 head); 4 independent waves x 16 q-rows.
// q,k: bf16 [S][heads*128] (roped); vT: bf16 [KVH*128][S]; o: bf16 [S][2048].
// Per kv-tile(32): QK^T = 8 MFMA, PV = 8 MFMA; P redistributed via per-wave LDS.
// No block-wide barriers (waves have different causal trip counts).
// ---------------------------------------------------------------------------
__global__ __launch_bounds__(256) void attn_kernel(
    const unsigned short* __restrict__ q, const unsigned short* __restrict__ kk,
    const unsigned short* __restrict__ vT, unsigned short* __restrict__ o)
{
    __shared__ unsigned short P[4][2][16][40];   // [wave][dbuf][row][col(pad)]
    const int tid = threadIdx.x, wave = tid >> 6, lane = tid & 63;
    const int h = blockIdx.y, kvh = h >> 1;
    const int q0 = blockIdx.x * 64 + wave * 16;
    const int lr = lane & 15, lg = lane >> 4;

    short8 qf[4];
    #pragma unroll
    for (int kf = 0; kf < 4; kf++)
        qf[kf] = *(const short8*)(q + (size_t)(q0 + lr) * 2048 + h * 128 + kf * 32 + 8 * lg);

    f32x4 acc[8];
    #pragma unroll
    for (int i = 0; i < 8; i++) acc[i] = (f32x4){0.f, 0.f, 0.f, 0.f};
    float m_[4] = {-3e38f, -3e38f, -3e38f, -3e38f};
    float l_[4] = {0.f, 0.f, 0.f, 0.f};
    const float scale = 0.08838834764831845f;  // 1/sqrt(128)

    int pb = 0;
    for (int kv0 = 0; kv0 <= q0 + 15; kv0 += 32, pb ^= 1) {
        f32x4 s0 = (f32x4){0.f, 0.f, 0.f, 0.f}, s1 = s0;
        const unsigned short* kb = kk + kvh * 128 + 8 * lg;
        #pragma unroll
        for (int kf = 0; kf < 4; kf++) {
            short8 k0v = *(const short8*)(kb + (size_t)(kv0 + lr) * 1024 + kf * 32);
            short8 k1v = *(const short8*)(kb + (size_t)(kv0 + 16 + lr) * 1024 + kf * 32);
            s0 = MFMA_BF16(qf[kf], k0v, s0);
            s1 = MFMA_BF16(qf[kf], k1v, s1);
        }
        float p[8];  // [nf*4 + reg]
        #pragma unroll
        for (int nf = 0; nf < 2; nf++)
            #pragma unroll
            for (int r = 0; r < 4; r++) {
                float sv = (nf ? s1[r] : s0[r]) * scale;
                const int qr = q0 + lg * 4 + r;
                const int kc = kv0 + nf * 16 + lr;
                if (kc > qr) sv = -1e9f;
                p[nf * 4 + r] = sv;
            }
        #pragma unroll
        for (int r = 0; r < 4; r++) {
            float mr = fmaxf(p[r], p[4 + r]);
            #pragma unroll
            for (int off = 1; off < 16; off <<= 1) mr = fmaxf(mr, __shfl_xor(mr, off));
            const float mnew = fmaxf(m_[r], mr);
            const float alpha = __expf(m_[r] - mnew);
            m_[r] = mnew;
            const float p0 = __expf(p[r] - mnew);
            const float p1 = __expf(p[4 + r] - mnew);
            p[r] = p0; p[4 + r] = p1;
            float rs = p0 + p1;
            #pragma unroll
            for (int off = 1; off < 16; off <<= 1) rs += __shfl_xor(rs, off);
            l_[r] = l_[r] * alpha + rs;
            #pragma unroll
            for (int nf = 0; nf < 8; nf++) acc[nf][r] *= alpha;
        }
        #pragma unroll
        for (int nf = 0; nf < 2; nf++)
            #pragma unroll
            for (int r = 0; r < 4; r++)
                P[wave][pb][lg * 4 + r][nf * 16 + lr] = f2b_bits(p[nf * 4 + r]);
        asm volatile("s_waitcnt lgkmcnt(0)" ::: "memory");
        const short8 pa = *(const short8*)&P[wave][pb][lr][8 * lg];
        #pragma unroll
        for (int nf = 0; nf < 8; nf++) {
            short8 vf = *(const short8*)(vT + (size_t)(kvh * 128 + nf * 16 + lr) * 2048 + kv0 + 8 * lg);
            acc[nf] = MFMA_BF16(pa, vf, acc[nf]);
        }
    }
    float inv[4];
    #pragma unroll
    for (int r = 0; r < 4; r++) inv[r] = 1.0f / l_[r];
    #pragma unroll
    for (int nf = 0; nf < 8; nf++)
        #pragma unroll
        for (int r = 0; r < 4; r++)
            o[(size_t)(q0 + lg * 4 + r) * 2048 + h * 128 + nf * 16 + lr] =
                f2b_bits(acc[nf][r] * inv[r]);
}

// ---------------------------------------------------------------------------
extern "C" void kernel_launch(void* const* d_in, const int* in_sizes, int n_in,
                              void* d_out, int out_size, void* d_ws, size_t ws_size,
                              hipStream_t stream) {
    (void)in_sizes; (void)n_in; (void)out_size; (void)ws_size;
    const float* x     = (const float*)d_in[0];
    const float* vec   = (const float*)d_in[1];
    const float* cosb  = (const float*)d_in[2];
    const float* sinb  = (const float*)d_in[3];
    // d_in[4] = mask: causal, reproduced analytically
    const float* wq    = (const float*)d_in[5];
    const float* wk    = (const float*)d_in[6];
    const float* wv    = (const float*)d_in[7];
    const float* wo    = (const float*)d_in[8];
    const float* w1    = (const float*)d_in[9];
    const float* w2    = (const float*)d_in[10];
    const float* w3    = (const float*)d_in[11];
    const float* mod_w = (const float*)d_in[12];
    const float* mod_b = (const float*)d_in[13];
    const float* anw   = (const float*)d_in[14];
    const float* fnw   = (const float*)d_in[15];
    float* out = (float*)d_out;

    char* ws = (char*)d_ws;
    size_t off = 0;
    auto alloc = [&](size_t bytes) -> void* {
        void* p = ws + off; off += (bytes + 255) & ~(size_t)255; return p;
    };
    unsigned short* WTq = (unsigned short*)alloc((size_t)2048 * 2048 * 2);
    unsigned short* WTk = (unsigned short*)alloc((size_t)1024 * 2048 * 2);
    unsigned short* WTv = (unsigned short*)alloc((size_t)1024 * 2048 * 2);
    unsigned short* WTo = (unsigned short*)alloc((size_t)2048 * 2048 * 2);
    unsigned short* WT1 = (unsigned short*)alloc((size_t)5632 * 2048 * 2);
    unsigned short* WT3 = (unsigned short*)alloc((size_t)5632 * 2048 * 2);
    unsigned short* WT2 = (unsigned short*)alloc((size_t)2048 * 5632 * 2);
    float* sv   = (float*)alloc((size_t)8 * 2048 * 4);
    float* modb = (float*)alloc((size_t)8 * 6144 * 4);
    unsigned short* h    = (unsigned short*)alloc((size_t)2048 * 2048 * 2);  // also hn
    unsigned short* qb   = (unsigned short*)alloc((size_t)2048 * 2048 * 2);
    unsigned short* kb   = (unsigned short*)alloc((size_t)2048 * 1024 * 2);
    unsigned short* vT   = (unsigned short*)alloc((size_t)1024 * 2048 * 2);
    unsigned short* ob   = (unsigned short*)alloc((size_t)2048 * 2048 * 2);
    unsigned short* u    = (unsigned short*)alloc((size_t)2048 * 5632 * 2);  // q_raw aliases
    unsigned short* ffin = (unsigned short*)alloc((size_t)2048 * 5632 * 2);  // k_raw aliases
    unsigned short* q_raw = u;     // lifetime-disjoint alias
    unsigned short* k_raw = ffin;  // lifetime-disjoint alias

    // Weights -> bf16 transposed
    transpose_kernel<<<dim3(32, 32), 256, 0, stream>>>(wq, WTq, 2048, 2048);
    transpose_kernel<<<dim3(16, 32), 256, 0, stream>>>(wk, WTk, 2048, 1024);
    transpose_kernel<<<dim3(16, 32), 256, 0, stream>>>(wv, WTv, 2048, 1024);
    transpose_kernel<<<dim3(32, 32), 256, 0, stream>>>(wo, WTo, 2048, 2048);
    transpose_kernel<<<dim3(88, 32), 256, 0, stream>>>(w1, WT1, 2048, 5632);
    transpose_kernel<<<dim3(88, 32), 256, 0, stream>>>(w3, WT3, 2048, 5632);
    transpose_kernel<<<dim3(32, 88), 256, 0, stream>>>(w2, WT2, 5632, 2048);

    // Modulation
    silu_kernel<<<64, 256, 0, stream>>>(vec, sv, 8 * 2048);
    mod_gemm_kernel<<<dim3(24, 8), 256, 0, stream>>>(sv, mod_w, mod_b, modb);

    // h = (1+scale)*rmsnorm(x)*anw + shift   (bf16)
    norm_kernel<true><<<2048, 256, 0, stream>>>(x, anw, modb, h);

    // QKV
    gemm_kernel<EP_BF16><<<dim3(16, 16), 256, 0, stream>>>(h, WTq, q_raw, nullptr, nullptr, nullptr, 2048, 2048, 2048);
    gemm_kernel<EP_BF16><<<dim3(8, 16), 256, 0, stream>>>(h, WTk, k_raw, nullptr, nullptr, nullptr, 2048, 1024, 2048);
    gemm_kernel<EP_VT><<<dim3(8, 16), 256, 0, stream>>>(h, WTv, vT, nullptr, nullptr, nullptr, 2048, 1024, 2048);

    // RoPE
    rope_kernel<16><<<8192, 256, 0, stream>>>(q_raw, qb, cosb, sinb);
    rope_kernel<8><<<4096, 256, 0, stream>>>(k_raw, kb, cosb, sinb);

    // Attention
    attn_kernel<<<dim3(32, 16), 256, 0, stream>>>(qb, kb, vT, ob);

    // x_mid = x + gate * (o @ wo)   -> d_out (f32)
    gemm_kernel<EP_XGATE><<<dim3(16, 16), 256, 0, stream>>>(ob, WTo, out, x, modb, nullptr, 2048, 2048, 2048);

    // hn = rmsnorm(x_mid)*fnw  (bf16, reuses h)
    norm_kernel<false><<<2048, 256, 0, stream>>>(out, fnw, nullptr, h);

    // FFN: u = hn@w1 ; ffin = silu(u)*(hn@w3) ; out += ffin@w2
    gemm_kernel<EP_BF16><<<dim3(44, 16), 256, 0, stream>>>(h, WT1, u, nullptr, nullptr, nullptr, 2048, 5632, 2048);
    gemm_kernel<EP_SILUMUL><<<dim3(44, 16), 256, 0, stream>>>(h, WT3, ffin, nullptr, nullptr, u, 2048, 5632, 2048);
    gemm_kernel<EP_ADDOUT><<<dim3(16, 16), 256, 0, stream>>>(ffin, WT2, out, nullptr, nullptr, nullptr, 2048, 2048, 5632);
}

// Round 2
// 785.842 us; speedup vs baseline: 1.2534x; 1.2534x over previous
//
#include <hip/hip_runtime.h>
#include <hip/hip_bf16.h>

// ---------------------------------------------------------------------------
// TokenFlowModel block on MI355X (gfx950).  Round 2.
// B=1, S=2048, D=2048, H=16, KVH=8, HD=128, FH=5632, M_=8, N_=256.
// GEMMs: m97-style 128x128 tile, BK=32, global_load_lds width-16 staging.
// Attention: 32x32x16 MFMA, swapped QK^T (lane-local softmax), no K/V LDS
// (L2-resident, head-pinned per XCD), exact causal balance via tile pairing.
// ---------------------------------------------------------------------------

typedef __attribute__((ext_vector_type(8))) short short8;   // 8 x bf16
typedef __attribute__((ext_vector_type(4))) float f32x4;
typedef __attribute__((ext_vector_type(16))) float f32x16;
typedef __attribute__((ext_vector_type(4))) unsigned short u16x4;

#define MFMA16(a, b, c) __builtin_amdgcn_mfma_f32_16x16x32_bf16((a), (b), (c), 0, 0, 0)
#define MFMA32(a, b, c) __builtin_amdgcn_mfma_f32_32x32x16_bf16((a), (b), (c), 0, 0, 0)

__device__ __forceinline__ unsigned short f2b_bits(float f) {
    union { float f; unsigned int u; } cv; cv.f = f;
    unsigned int u = cv.u;
    u += 0x7fffu + ((u >> 16) & 1u);   // round-to-nearest-even
    return (unsigned short)(u >> 16);
}
__device__ __forceinline__ float b2f_bits(unsigned short b) {
    union { float f; unsigned int u; } cv; cv.u = ((unsigned int)b) << 16; return cv.f;
}
__device__ __forceinline__ float silu_f(float x) { return x / (1.0f + __expf(-x)); }

// async global->LDS, 16B per lane.  LDS dest: wave-uniform base + lane*16.
__device__ __forceinline__ void async_copy16(const unsigned short* g, unsigned short* l) {
    __builtin_amdgcn_global_load_lds(
        (const __attribute__((address_space(1))) unsigned int*)g,
        (__attribute__((address_space(3))) unsigned int*)l, 16, 0, 0);
}

// ---------------------------------------------------------------------------
// Weight transpose + f32->bf16 (+ optional scale): W[K][N] -> WT[N][K] bf16
// ---------------------------------------------------------------------------
__global__ __launch_bounds__(256) void transpose_kernel(
    const float* __restrict__ W, unsigned short* __restrict__ WT, int K, int N,
    float scale)
{
    __shared__ float t[64][65];
    const int tid = threadIdx.x;
    const int k0 = blockIdx.y * 64, n0 = blockIdx.x * 64;
    {
        const int row = tid >> 2, cq = (tid & 3) * 16;
        const float* src = W + (size_t)(k0 + row) * N + n0 + cq;
        #pragma unroll
        for (int i = 0; i < 4; i++) {
            float4 v = *(const float4*)(src + i * 4);
            t[row][cq + i * 4 + 0] = v.x;
            t[row][cq + i * 4 + 1] = v.y;
            t[row][cq + i * 4 + 2] = v.z;
            t[row][cq + i * 4 + 3] = v.w;
        }
    }
    __syncthreads();
    {
        const int n = tid >> 2, kq = (tid & 3) * 16;
        short8 v0, v1;
        #pragma unroll
        for (int i = 0; i < 8; i++) {
            v0[i] = (short)f2b_bits(t[kq + i][n] * scale);
            v1[i] = (short)f2b_bits(t[kq + 8 + i][n] * scale);
        }
        unsigned short* dst = WT + (size_t)(n0 + n) * K + k0 + kq;
        *(short8*)(dst) = v0;
        *(short8*)(dst + 8) = v1;
    }
}

// ---------------------------------------------------------------------------
// silu(vec) -> svec   (8 x 2048)
// ---------------------------------------------------------------------------
__global__ void silu_kernel(const float* __restrict__ in, float* __restrict__ outp, int n) {
    int i = blockIdx.x * 256 + threadIdx.x;
    if (i < n) outp[i] = silu_f(in[i]);
}

// ---------------------------------------------------------------------------
// mod GEMM pass 1: part[kc][m][6144] partial sums (mod_w read exactly once)
// grid (24 nblk, 8 kc)
// ---------------------------------------------------------------------------
__global__ __launch_bounds__(256) void mod_gemm1(
    const float* __restrict__ svec, const float* __restrict__ mw,
    float* __restrict__ part)
{
    __shared__ float svs[8][256];
    const int tid = threadIdx.x;
    const int nb = blockIdx.x, kc = blockIdx.y;
    const int n = nb * 256 + tid;
    #pragma unroll
    for (int m8 = 0; m8 < 8; m8++) svs[m8][tid] = svec[m8 * 2048 + kc * 256 + tid];
    __syncthreads();
    float acc[8];
    #pragma unroll
    for (int m = 0; m < 8; m++) acc[m] = 0.0f;
    for (int k = 0; k < 256; k++) {
        const float w = mw[(size_t)(kc * 256 + k) * 6144 + n];
        #pragma unroll
        for (int m = 0; m < 8; m++) acc[m] += svs[m][k] * w;
    }
    #pragma unroll
    for (int m = 0; m < 8; m++) part[(size_t)(kc * 8 + m) * 6144 + n] = acc[m];
}

// pass 2: modb[m][6144] = sum_kc part + mb  (fixed order -> deterministic)
__global__ void mod_gemm2(const float* __restrict__ part, const float* __restrict__ mb,
                          float* __restrict__ modb)
{
    const int i = blockIdx.x * 256 + threadIdx.x;   // 8*6144
    const int n = i % 6144;
    float a = mb[n];
    #pragma unroll
    for (int kc = 0; kc < 8; kc++) a += part[(size_t)(kc * 8 + (i / 6144)) * 6144 + n];
    modb[i] = a;
}

// ---------------------------------------------------------------------------
// RMSNorm (+ optional AdaLN modulation) -> bf16 row.  One block per row.
// ---------------------------------------------------------------------------
template<bool MOD>
__global__ __launch_bounds__(256) void norm_kernel(
    const float* __restrict__ xin, const float* __restrict__ w,
    const float* __restrict__ mod, unsigned short* __restrict__ outp)
{
    const int s = blockIdx.x, tid = threadIdx.x;
    const float* xr = xin + (size_t)s * 2048;
    float4 a4 = *(const float4*)(xr + tid * 8);
    float4 b4 = *(const float4*)(xr + tid * 8 + 4);
    float v[8] = {a4.x, a4.y, a4.z, a4.w, b4.x, b4.y, b4.z, b4.w};
    float ss = 0.0f;
    #pragma unroll
    for (int i = 0; i < 8; i++) ss += v[i] * v[i];
    #pragma unroll
    for (int off = 1; off < 64; off <<= 1) ss += __shfl_xor(ss, off);
    __shared__ float red[4];
    if ((tid & 63) == 0) red[tid >> 6] = ss;
    __syncthreads();
    ss = red[0] + red[1] + red[2] + red[3];
    const float inv = rsqrtf(ss * (1.0f / 2048.0f) + 1e-6f);
    const int g = s >> 8;
    #pragma unroll
    for (int i = 0; i < 8; i++) {
        const int d = tid * 8 + i;
        float y = v[i] * inv * w[d];
        if (MOD) y = y * (1.0f + mod[g * 6144 + 2048 + d]) + mod[g * 6144 + d];
        outp[(size_t)s * 2048 + d] = f2b_bits(y);
    }
}

// ---------------------------------------------------------------------------
// Rope (interleaved pairs). in/out: [S][HEADS][128] bf16. One thread per pair.
// ---------------------------------------------------------------------------
template<int HEADS>
__global__ __launch_bounds__(256) void rope_kernel(
    const unsigned short* __restrict__ in, unsigned short* __restrict__ outp,
    const float* __restrict__ ct, const float* __restrict__ st)
{
    const int idx = blockIdx.x * 256 + threadIdx.x;   // pair index
    const int p = idx & 63;
    const int s = idx / (HEADS * 64);
    const float c = ct[s * 64 + p], sn = st[s * 64 + p];
    const unsigned int pr = *(const unsigned int*)(in + (size_t)idx * 2);
    const float xr = b2f_bits((unsigned short)(pr & 0xffffu));
    const float xi = b2f_bits((unsigned short)(pr >> 16));
    const unsigned int lo = f2b_bits(xr * c - xi * sn);
    const unsigned int hi = f2b_bits(xr * sn + xi * c);
    *(unsigned int*)(outp + (size_t)idx * 2) = lo | (hi << 16);
}

// ---------------------------------------------------------------------------
// bf16 GEMM, m97 structure: C[M][N] = A[M][K] @ BT[N][K]^T, f32 accum.
// 128x128 tile, BK=32, linear LDS, global_load_lds width-16 staging.
// ---------------------------------------------------------------------------
enum { EP_BF16 = 0, EP_KV = 1, EP_XGATE = 2, EP_SILUMUL = 3, EP_ADDOUT = 4 };

template<int EPI>
__global__ __launch_bounds__(256) void gemm_kernel(
    const unsigned short* __restrict__ A, const unsigned short* __restrict__ BT,
    void* __restrict__ outp, void* __restrict__ outp2,
    const float* __restrict__ xin,   // EP_XGATE: residual x
    const float* __restrict__ modp,  // EP_XGATE: mod (gate at +4096)
    const unsigned short* __restrict__ up,  // EP_SILUMUL: u = hn@w1 (bf16)
    int M, int N, int K)
{
    __shared__ unsigned short As[128 * 32];
    __shared__ unsigned short Bs[128 * 32];
    const int tid = threadIdx.x;
    const int lane = tid & 63, wave = tid >> 6;
    const int m0 = blockIdx.y * 128, n0 = blockIdx.x * 128;
    const int wr = (wave >> 1) * 64, wc = (wave & 1) * 64;
    const int lr = lane & 15, lg = lane >> 4;

    // staging map: LDS byte = wave*2048 + issue*1024 + lane*16
    //   -> row = wave*32 + issue*16 + (lane>>2), col = (lane&3)*8 shorts
    const int srow = wave * 32 + (lane >> 2);
    const int scol = (lane & 3) * 8;
    const unsigned short* pA0 = A + (size_t)(m0 + srow) * K + scol;
    const unsigned short* pA1 = pA0 + (size_t)16 * K;
    const unsigned short* pB0 = BT + (size_t)(n0 + srow) * K + scol;
    const unsigned short* pB1 = pB0 + (size_t)16 * K;
    unsigned short* lA0 = &As[wave * 1024];
    unsigned short* lA1 = &As[wave * 1024 + 512];
    unsigned short* lB0 = &Bs[wave * 1024];
    unsigned short* lB1 = &Bs[wave * 1024 + 512];

    f32x4 acc[4][4];
    #pragma unroll
    for (int i = 0; i < 4; i++)
        #pragma unroll
        for (int j = 0; j < 4; j++) acc[i][j] = (f32x4){0.f, 0.f, 0.f, 0.f};

    for (int k0 = 0; k0 < K; k0 += 32) {
        __syncthreads();
        async_copy16(pA0 + k0, lA0);
        async_copy16(pA1 + k0, lA1);
        async_copy16(pB0 + k0, lB0);
        async_copy16(pB1 + k0, lB1);
        __syncthreads();   // compiler drains vmcnt before barrier
        short8 af[4], bfr[4];
        #pragma unroll
        for (int i = 0; i < 4; i++) {
            af[i]  = *(const short8*)&As[(wr + i * 16 + lr) * 32 + 8 * lg];
            bfr[i] = *(const short8*)&Bs[(wc + i * 16 + lr) * 32 + 8 * lg];
        }
        #pragma unroll
        for (int i = 0; i < 4; i++)
            #pragma unroll
            for (int j = 0; j < 4; j++)
                acc[i][j] = MFMA16(af[i], bfr[j], acc[i][j]);
    }

    // Epilogue. D layout: row = (lane>>4)*4 + reg, col = lane&15.
    #pragma unroll
    for (int i = 0; i < 4; i++) {
        #pragma unroll
        for (int j = 0; j < 4; j++) {
            const int rb = m0 + wr + i * 16 + lg * 4;
            const int c  = n0 + wc + j * 16 + lr;
            if constexpr (EPI == EP_KV) {
                if (n0 < 1024) {   // K half -> k_raw [S][1024] bf16
                    #pragma unroll
                    for (int r = 0; r < 4; r++)
                        ((unsigned short*)outp)[(size_t)(rb + r) * 1024 + c] =
                            f2b_bits(acc[i][j][r]);
                } else {           // V half -> vT [1024][S] bf16 (transposed)
                    u16x4 pk4;
                    #pragma unroll
                    for (int r = 0; r < 4; r++) pk4[r] = f2b_bits(acc[i][j][r]);
                    *(u16x4*)((unsigned short*)outp2 + (size_t)(c - 1024) * 2048 + rb) = pk4;
                }
            } else {
                #pragma unroll
                for (int r = 0; r < 4; r++) {
                    const int row = rb + r;
                    const size_t idx = (size_t)row * N + c;
                    const float v = acc[i][j][r];
                    if constexpr (EPI == EP_BF16) {
                        ((unsigned short*)outp)[idx] = f2b_bits(v);
                    } else if constexpr (EPI == EP_XGATE) {
                        ((float*)outp)[idx] = xin[idx] + modp[(row >> 8) * 6144 + 4096 + c] * v;
                    } else if constexpr (EPI == EP_SILUMUL) {
                        const float uu = b2f_bits(up[idx]);
                        ((unsigned short*)outp)[idx] = f2b_bits(silu_f(uu) * v);
                    } else {  // EP_ADDOUT
                        ((float*)outp)[idx] = ((float*)outp)[idx] + v;
                    }
                }
            }
        }
    }
}

// ---------------------------------------------------------------------------
// Flash attention, causal, GQA.  8 waves x 32 q-rows, 32x32x16 MFMA.
// Swapped QK^T: S^T = mfma(K, Q)  -> lane l5 owns q-row q0+l5 (in-lane softmax).
// P -> PV B-operand via packed-bf16 shfl_xor(32) exchange.  PV: O^T = mfma(V^T, P^T).
// Tile pairing: wave w<4 gets tile 4*bq+w, w>=4 gets 63-(4*bq+w-4)  (uniform work).
// q pre-scaled by 1/sqrt(128).  Epilogue: O^T -> LDS -> coalesced O store.
// ---------------------------------------------------------------------------
__global__ __launch_bounds__(512, 2) void attn_kernel(
    const unsigned short* __restrict__ q,   // [S][2048] roped, scaled
    const unsigned short* __restrict__ kk,  // [S][1024] roped
    const unsigned short* __restrict__ vT,  // [1024][S]
    unsigned short* __restrict__ o)         // [S][2048]
{
    __shared__ unsigned short Ot[8][32][136];
    const int tid = threadIdx.x, wave = tid >> 6, lane = tid & 63;
    const int l5 = lane & 31, hi = lane >> 5;
    const int h = blockIdx.x, bq = blockIdx.y;   // head on x -> XCD-pinned KV
    const int j = 4 * bq + (wave & 3);
    const int tw = (wave < 4) ? j : (63 - j);
    const int q0 = tw * 32;
    const int kvh = h >> 1;
    const int qrow = q0 + l5;

    short8 qf[8];
    {
        const unsigned short* qp = q + (size_t)qrow * 2048 + h * 128 + hi * 8;
        #pragma unroll
        for (int kf = 0; kf < 8; kf++) qf[kf] = *(const short8*)(qp + kf * 16);
    }

    f32x16 ot[4];
    #pragma unroll
    for (int df = 0; df < 4; df++)
        #pragma unroll
        for (int r = 0; r < 16; r++) ot[df][r] = 0.0f;
    float m_ = -3e30f, l_ = 0.0f;

    const unsigned short* kbase = kk + kvh * 128 + hi * 8;
    const unsigned short* vbase = vT + (size_t)(kvh * 128) * 2048;
    const int niter = (q0 + 32 + 63) >> 6;

    for (int it = 0; it < niter; it++) {
        const int kv0 = it * 64;
        // ---- QK^T (swapped): st[nf] cols = q, rows = kv ----
        f32x16 st[2];
        #pragma unroll
        for (int nf = 0; nf < 2; nf++)
            #pragma unroll
            for (int r = 0; r < 16; r++) st[nf][r] = 0.0f;
        #pragma unroll
        for (int kf = 0; kf < 8; kf++) {
            const short8 k0v = *(const short8*)(kbase + (size_t)(kv0 + l5) * 1024 + kf * 16);
            const short8 k1v = *(const short8*)(kbase + (size_t)(kv0 + 32 + l5) * 1024 + kf * 16);
            st[0] = MFMA32(k0v, qf[kf], st[0]);
            st[1] = MFMA32(k1v, qf[kf], st[1]);
        }
        // ---- mask + online softmax (lane-local row) ----
        float sv[2][16];
        #pragma unroll
        for (int nf = 0; nf < 2; nf++)
            #pragma unroll
            for (int r = 0; r < 16; r++) {
                const int kvi = kv0 + nf * 32 + (r & 3) + 8 * (r >> 2) + 4 * hi;
                sv[nf][r] = (kvi > qrow) ? -3e30f : st[nf][r];
            }
        float pmax = sv[0][0];
        #pragma unroll
        for (int nf = 0; nf < 2; nf++)
            #pragma unroll
            for (int r = 0; r < 16; r++) pmax = fmaxf(pmax, sv[nf][r]);
        pmax = fmaxf(pmax, __shfl_xor(pmax, 32));
        const float mnew = fmaxf(m_, pmax);
        const float alpha = __expf(m_ - mnew);
        m_ = mnew;
        float rs = 0.0f;
        #pragma unroll
        for (int nf = 0; nf < 2; nf++)
            #pragma unroll
            for (int r = 0; r < 16; r++) {
                const float p = __expf(sv[nf][r] - mnew);
                sv[nf][r] = p;
                rs += p;
            }
        rs += __shfl_xor(rs, 32);
        l_ = l_ * alpha + rs;
        #pragma unroll
        for (int df = 0; df < 4; df++)
            #pragma unroll
            for (int r = 0; r < 16; r++) ot[df][r] *= alpha;
        // ---- pack P to bf16 + cross-half exchange -> PV B-frags ----
        short8 pa[4];
        #pragma unroll
        for (int nf = 0; nf < 2; nf++) {
            #pragma unroll
            for (int hh = 0; hh < 2; hh++) {
                unsigned int a0 = ((unsigned int)f2b_bits(sv[nf][8 * hh + 1]) << 16) | f2b_bits(sv[nf][8 * hh + 0]);
                unsigned int a1 = ((unsigned int)f2b_bits(sv[nf][8 * hh + 3]) << 16) | f2b_bits(sv[nf][8 * hh + 2]);
                unsigned int a2 = ((unsigned int)f2b_bits(sv[nf][8 * hh + 5]) << 16) | f2b_bits(sv[nf][8 * hh + 4]);
                unsigned int a3 = ((unsigned int)f2b_bits(sv[nf][8 * hh + 7]) << 16) | f2b_bits(sv[nf][8 * hh + 6]);
                const unsigned int x0 = (unsigned int)__shfl_xor((int)a0, 32);
                const unsigned int x1 = (unsigned int)__shfl_xor((int)a1, 32);
                const unsigned int x2 = (unsigned int)__shfl_xor((int)a2, 32);
                const unsigned int x3 = (unsigned int)__shfl_xor((int)a3, 32);
                union { unsigned int u[4]; short8 s; } cv;
                cv.u[0] = hi ? x2 : a0;
                cv.u[1] = hi ? x3 : a1;
                cv.u[2] = hi ? a2 : x0;
                cv.u[3] = hi ? a3 : x1;
                pa[nf * 2 + hh] = cv.s;
            }
        }
        // ---- PV (swapped): ot[df] += V^T frag x P^T frag ----
        #pragma unroll
        for (int df = 0; df < 4; df++) {
            #pragma unroll
            for (int kvf = 0; kvf < 4; kvf++) {
                const short8 vfrag = *(const short8*)(
                    vbase + (size_t)(df * 32 + l5) * 2048 + kv0 + kvf * 16 + hi * 8);
                ot[df] = MFMA32(vfrag, pa[kvf], ot[df]);
            }
        }
    }

    // ---- epilogue: normalize, transpose via LDS, coalesced store ----
    const float rinv = 1.0f / l_;
    #pragma unroll
    for (int df = 0; df < 4; df++)
        #pragma unroll
        for (int r = 0; r < 16; r++) {
            const int d = df * 32 + (r & 3) + 8 * (r >> 2) + 4 * hi;
            Ot[wave][l5][d] = f2b_bits(ot[df][r] * rinv);
        }
    asm volatile("s_waitcnt lgkmcnt(0)" ::: "memory");
    __builtin_amdgcn_sched_barrier(0);
    #pragma unroll
    for (int jj = 0; jj < 8; jj++) {
        const int row = jj * 4 + (lane >> 4);
        const int ch = lane & 15;
        const short8 vv = *(const short8*)&Ot[wave][row][ch * 8];
        *(short8*)(o + (size_t)(q0 + row) * 2048 + h * 128 + ch * 8) = vv;
    }
}

// ---------------------------------------------------------------------------
extern "C" void kernel_launch(void* const* d_in, const int* in_sizes, int n_in,
                              void* d_out, int out_size, void* d_ws, size_t ws_size,
                              hipStream_t stream) {
    (void)in_sizes; (void)n_in; (void)out_size; (void)ws_size;
    const float* x     = (const float*)d_in[0];
    const float* vec   = (const float*)d_in[1];
    const float* cosb  = (const float*)d_in[2];
    const float* sinb  = (const float*)d_in[3];
    // d_in[4] = mask: causal, reproduced analytically
    const float* wq    = (const float*)d_in[5];
    const float* wk    = (const float*)d_in[6];
    const float* wv    = (const float*)d_in[7];
    const float* wo    = (const float*)d_in[8];
    const float* w1    = (const float*)d_in[9];
    const float* w2    = (const float*)d_in[10];
    const float* w3    = (const float*)d_in[11];
    const float* mod_w = (const float*)d_in[12];
    const float* mod_b = (const float*)d_in[13];
    const float* anw   = (const float*)d_in[14];
    const float* fnw   = (const float*)d_in[15];
    float* out = (float*)d_out;

    char* ws = (char*)d_ws;
    size_t off = 0;
    auto alloc = [&](size_t bytes) -> void* {
        void* p = ws + off; off += (bytes + 255) & ~(size_t)255; return p;
    };
    unsigned short* WTq  = (unsigned short*)alloc((size_t)2048 * 2048 * 2);
    unsigned short* WTkv = (unsigned short*)alloc((size_t)2048 * 2048 * 2);  // [wk ; wv]
    unsigned short* WTo  = (unsigned short*)alloc((size_t)2048 * 2048 * 2);
    unsigned short* WT1  = (unsigned short*)alloc((size_t)5632 * 2048 * 2);
    unsigned short* WT3  = (unsigned short*)alloc((size_t)5632 * 2048 * 2);
    unsigned short* WT2  = (unsigned short*)alloc((size_t)2048 * 5632 * 2);
    float* svec = (float*)alloc((size_t)8 * 2048 * 4);
    float* part = (float*)alloc((size_t)64 * 6144 * 4);
    float* modb = (float*)alloc((size_t)8 * 6144 * 4);
    unsigned short* h    = (unsigned short*)alloc((size_t)2048 * 2048 * 2);  // also hn
    unsigned short* qb   = (unsigned short*)alloc((size_t)2048 * 2048 * 2);
    unsigned short* kb   = (unsigned short*)alloc((size_t)2048 * 1024 * 2);
    unsigned short* vT   = (unsigned short*)alloc((size_t)1024 * 2048 * 2);
    unsigned short* ob   = (unsigned short*)alloc((size_t)2048 * 2048 * 2);
    unsigned short* u    = (unsigned short*)alloc((size_t)2048 * 5632 * 2);
    unsigned short* ffin = (unsigned short*)alloc((size_t)2048 * 5632 * 2);
    unsigned short* q_raw = u;     // lifetime-disjoint alias
    unsigned short* k_raw = ffin;  // lifetime-disjoint alias

    const float qscale = 0.08838834764831845f;  // 1/sqrt(128) folded into Wq

    // Weights -> bf16 transposed
    transpose_kernel<<<dim3(32, 32), 256, 0, stream>>>(wq, WTq, 2048, 2048, qscale);
    transpose_kernel<<<dim3(16, 32), 256, 0, stream>>>(wk, WTkv, 2048, 1024, 1.0f);
    transpose_kernel<<<dim3(16, 32), 256, 0, stream>>>(wv, WTkv + (size_t)1024 * 2048, 2048, 1024, 1.0f);
    transpose_kernel<<<dim3(32, 32), 256, 0, stream>>>(wo, WTo, 2048, 2048, 1.0f);
    transpose_kernel<<<dim3(88, 32), 256, 0, stream>>>(w1, WT1, 2048, 5632, 1.0f);
    transpose_kernel<<<dim3(88, 32), 256, 0, stream>>>(w3, WT3, 2048, 5632, 1.0f);
    transpose_kernel<<<dim3(32, 88), 256, 0, stream>>>(w2, WT2, 5632, 2048, 1.0f);

    // Modulation
    silu_kernel<<<64, 256, 0, stream>>>(vec, svec, 8 * 2048);
    mod_gemm1<<<dim3(24, 8), 256, 0, stream>>>(svec, mod_w, part);
    mod_gemm2<<<192, 256, 0, stream>>>(part, mod_b, modb);

    // h = (1+scale)*rmsnorm(x)*anw + shift   (bf16)
    norm_kernel<true><<<2048, 256, 0, stream>>>(x, anw, modb, h);

    // Q and fused K|V GEMMs
    gemm_kernel<EP_BF16><<<dim3(16, 16), 256, 0, stream>>>(h, WTq, q_raw, nullptr, nullptr, nullptr, nullptr, 2048, 2048, 2048);
    gemm_kernel<EP_KV><<<dim3(16, 16), 256, 0, stream>>>(h, WTkv, k_raw, vT, nullptr, nullptr, nullptr, 2048, 2048, 2048);

    // RoPE
    rope_kernel<16><<<8192, 256, 0, stream>>>(q_raw, qb, cosb, sinb);
    rope_kernel<8><<<4096, 256, 0, stream>>>(k_raw, kb, cosb, sinb);

    // Attention (head on blockIdx.x for XCD L2 locality)
    attn_kernel<<<dim3(16, 16), 512, 0, stream>>>(qb, kb, vT, ob);

    // x_mid = x + gate * (o @ wo)   -> d_out (f32)
    gemm_kernel<EP_XGATE><<<dim3(16, 16), 256, 0, stream>>>(ob, WTo, out, nullptr, x, modb, nullptr, 2048, 2048, 2048);

    // hn = rmsnorm(x_mid)*fnw  (bf16, reuses h)
    norm_kernel<false><<<2048, 256, 0, stream>>>(out, fnw, nullptr, h);

    // FFN: u = hn@w1 ; ffin = silu(u)*(hn@w3) ; out += ffin@w2
    gemm_kernel<EP_BF16><<<dim3(44, 16), 256, 0, stream>>>(h, WT1, u, nullptr, nullptr, nullptr, nullptr, 2048, 5632, 2048);
    gemm_kernel<EP_SILUMUL><<<dim3(44, 16), 256, 0, stream>>>(h, WT3, ffin, nullptr, nullptr, nullptr, u, 2048, 5632, 2048);
    gemm_kernel<EP_ADDOUT><<<dim3(16, 16), 256, 0, stream>>>(ffin, WT2, out, nullptr, nullptr, nullptr, nullptr, 2048, 2048, 5632);
}

// Round 3
// 567.911 us; speedup vs baseline: 1.7344x; 1.3837x over previous
//
#include <hip/hip_runtime.h>
#include <hip/hip_bf16.h>

// ---------------------------------------------------------------------------
// TokenFlowModel block on MI355X (gfx950).  Round 3.
// B=1, S=2048, D=2048, H=16, KVH=8, HD=128, FH=5632, M_=8, N_=256.
// GEMMs: m97-style tiles (BM = 128 or 64 via template), BK=32,
//        global_load_lds width-16 staging.  QKV fused (N=4096).
// Attention: LDS-staged KV shared across 4 waves (2 heads x 2 kv-split),
//        XOR-swizzled chunks (pre-swizzled global source), 512 blocks LPT.
// ---------------------------------------------------------------------------

typedef __attribute__((ext_vector_type(8))) short short8;   // 8 x bf16
typedef __attribute__((ext_vector_type(4))) float f32x4;
typedef __attribute__((ext_vector_type(16))) float f32x16;
typedef __attribute__((ext_vector_type(4))) unsigned short u16x4;

#define MFMA16(a, b, c) __builtin_amdgcn_mfma_f32_16x16x32_bf16((a), (b), (c), 0, 0, 0)
#define MFMA32(a, b, c) __builtin_amdgcn_mfma_f32_32x32x16_bf16((a), (b), (c), 0, 0, 0)

__device__ __forceinline__ unsigned short f2b_bits(float f) {
    union { float f; unsigned int u; } cv; cv.f = f;
    unsigned int u = cv.u;
    u += 0x7fffu + ((u >> 16) & 1u);   // round-to-nearest-even
    return (unsigned short)(u >> 16);
}
__device__ __forceinline__ float b2f_bits(unsigned short b) {
    union { float f; unsigned int u; } cv; cv.u = ((unsigned int)b) << 16; return cv.f;
}
__device__ __forceinline__ float silu_f(float x) { return x / (1.0f + __expf(-x)); }

// async global->LDS, 16B per lane.  LDS dest: wave-uniform base + lane*16.
__device__ __forceinline__ void async_copy16(const unsigned short* g, unsigned short* l) {
    __builtin_amdgcn_global_load_lds(
        (const __attribute__((address_space(1))) unsigned int*)g,
        (__attribute__((address_space(3))) unsigned int*)l, 16, 0, 0);
}

// ---------------------------------------------------------------------------
// Weight transpose + f32->bf16 (+ optional scale): W[K][N] -> WT[N][K] bf16
// ---------------------------------------------------------------------------
__global__ __launch_bounds__(256) void transpose_kernel(
    const float* __restrict__ W, unsigned short* __restrict__ WT, int K, int N,
    float scale)
{
    __shared__ float t[64][65];
    const int tid = threadIdx.x;
    const int k0 = blockIdx.y * 64, n0 = blockIdx.x * 64;
    {
        const int row = tid >> 2, cq = (tid & 3) * 16;
        const float* src = W + (size_t)(k0 + row) * N + n0 + cq;
        #pragma unroll
        for (int i = 0; i < 4; i++) {
            float4 v = *(const float4*)(src + i * 4);
            t[row][cq + i * 4 + 0] = v.x;
            t[row][cq + i * 4 + 1] = v.y;
            t[row][cq + i * 4 + 2] = v.z;
            t[row][cq + i * 4 + 3] = v.w;
        }
    }
    __syncthreads();
    {
        const int n = tid >> 2, kq = (tid & 3) * 16;
        short8 v0, v1;
        #pragma unroll
        for (int i = 0; i < 8; i++) {
            v0[i] = (short)f2b_bits(t[kq + i][n] * scale);
            v1[i] = (short)f2b_bits(t[kq + 8 + i][n] * scale);
        }
        unsigned short* dst = WT + (size_t)(n0 + n) * K + k0 + kq;
        *(short8*)(dst) = v0;
        *(short8*)(dst + 8) = v1;
    }
}

// ---------------------------------------------------------------------------
// silu(vec) -> svec   (8 x 2048)
// ---------------------------------------------------------------------------
__global__ void silu_kernel(const float* __restrict__ in, float* __restrict__ outp, int n) {
    int i = blockIdx.x * 256 + threadIdx.x;
    if (i < n) outp[i] = silu_f(in[i]);
}

// ---------------------------------------------------------------------------
// mod GEMM pass 1: part[kc][m][6144] partial sums (mod_w read exactly once)
// ---------------------------------------------------------------------------
__global__ __launch_bounds__(256) void mod_gemm1(
    const float* __restrict__ svec, const float* __restrict__ mw,
    float* __restrict__ part)
{
    __shared__ float svs[8][256];
    const int tid = threadIdx.x;
    const int nb = blockIdx.x, kc = blockIdx.y;
    const int n = nb * 256 + tid;
    #pragma unroll
    for (int m8 = 0; m8 < 8; m8++) svs[m8][tid] = svec[m8 * 2048 + kc * 256 + tid];
    __syncthreads();
    float acc[8];
    #pragma unroll
    for (int m = 0; m < 8; m++) acc[m] = 0.0f;
    for (int k = 0; k < 256; k++) {
        const float w = mw[(size_t)(kc * 256 + k) * 6144 + n];
        #pragma unroll
        for (int m = 0; m < 8; m++) acc[m] += svs[m][k] * w;
    }
    #pragma unroll
    for (int m = 0; m < 8; m++) part[(size_t)(kc * 8 + m) * 6144 + n] = acc[m];
}

// pass 2: modb[m][6144] = sum_kc part + mb  (fixed order -> deterministic)
__global__ void mod_gemm2(const float* __restrict__ part, const float* __restrict__ mb,
                          float* __restrict__ modb)
{
    const int i = blockIdx.x * 256 + threadIdx.x;   // 8*6144
    const int n = i % 6144;
    float a = mb[n];
    #pragma unroll
    for (int kc = 0; kc < 8; kc++) a += part[(size_t)(kc * 8 + (i / 6144)) * 6144 + n];
    modb[i] = a;
}

// ---------------------------------------------------------------------------
// RMSNorm (+ optional AdaLN modulation) -> bf16 row.  One block per row.
// ---------------------------------------------------------------------------
template<bool MOD>
__global__ __launch_bounds__(256) void norm_kernel(
    const float* __restrict__ xin, const float* __restrict__ w,
    const float* __restrict__ mod, unsigned short* __restrict__ outp)
{
    const int s = blockIdx.x, tid = threadIdx.x;
    const float* xr = xin + (size_t)s * 2048;
    float4 a4 = *(const float4*)(xr + tid * 8);
    float4 b4 = *(const float4*)(xr + tid * 8 + 4);
    float v[8] = {a4.x, a4.y, a4.z, a4.w, b4.x, b4.y, b4.z, b4.w};
    float ss = 0.0f;
    #pragma unroll
    for (int i = 0; i < 8; i++) ss += v[i] * v[i];
    #pragma unroll
    for (int off = 1; off < 64; off <<= 1) ss += __shfl_xor(ss, off);
    __shared__ float red[4];
    if ((tid & 63) == 0) red[tid >> 6] = ss;
    __syncthreads();
    ss = red[0] + red[1] + red[2] + red[3];
    const float inv = rsqrtf(ss * (1.0f / 2048.0f) + 1e-6f);
    const int g = s >> 8;
    #pragma unroll
    for (int i = 0; i < 8; i++) {
        const int d = tid * 8 + i;
        float y = v[i] * inv * w[d];
        if (MOD) y = y * (1.0f + mod[g * 6144 + 2048 + d]) + mod[g * 6144 + d];
        outp[(size_t)s * 2048 + d] = f2b_bits(y);
    }
}

// ---------------------------------------------------------------------------
// Rope (interleaved pairs). in/out: [S][HEADS][128] bf16. One thread per pair.
// ---------------------------------------------------------------------------
template<int HEADS>
__global__ __launch_bounds__(256) void rope_kernel(
    const unsigned short* __restrict__ in, unsigned short* __restrict__ outp,
    const float* __restrict__ ct, const float* __restrict__ st)
{
    const int idx = blockIdx.x * 256 + threadIdx.x;   // pair index
    const int p = idx & 63;
    const int s = idx / (HEADS * 64);
    const float c = ct[s * 64 + p], sn = st[s * 64 + p];
    const unsigned int pr = *(const unsigned int*)(in + (size_t)idx * 2);
    const float xr = b2f_bits((unsigned short)(pr & 0xffffu));
    const float xi = b2f_bits((unsigned short)(pr >> 16));
    const unsigned int lo = f2b_bits(xr * c - xi * sn);
    const unsigned int hi = f2b_bits(xr * sn + xi * c);
    *(unsigned int*)(outp + (size_t)idx * 2) = lo | (hi << 16);
}

// ---------------------------------------------------------------------------
// bf16 GEMM, m97 structure: C[M][N] = A[M][K] @ BT[N][K]^T, f32 accum.
// Tile (RF*32) x 128, BK=32, linear LDS, global_load_lds width-16 staging.
// RF=4 -> 128x128 tile; RF=2 -> 64x128 tile (for shapes needing more blocks).
// ---------------------------------------------------------------------------
enum { EP_BF16 = 0, EP_QKV = 1, EP_XGATE = 2, EP_SILUMUL = 3, EP_ADDOUT = 4 };

template<int RF, int EPI>
__global__ __launch_bounds__(256) void gemm_kernel(
    const unsigned short* __restrict__ A, const unsigned short* __restrict__ BT,
    void* __restrict__ outp, void* __restrict__ outp2, void* __restrict__ outp3,
    const float* __restrict__ xin,   // EP_XGATE: residual x
    const float* __restrict__ modp,  // EP_XGATE: mod (gate at +4096)
    const unsigned short* __restrict__ up,  // EP_SILUMUL: u = hn@w1 (bf16)
    int M, int N, int K)
{
    __shared__ unsigned short As[RF * 32 * 32];
    __shared__ unsigned short Bs[128 * 32];
    const int tid = threadIdx.x;
    const int lane = tid & 63, wave = tid >> 6;
    const int m0 = blockIdx.y * (RF * 32), n0 = blockIdx.x * 128;
    const int wr = (wave >> 1) * (RF * 16), wc = (wave & 1) * 64;
    const int lr = lane & 15, lg = lane >> 4;
    const int nAi = RF / 2;   // A-staging instrs per wave (B is always 2)

    f32x4 acc[RF][4];
    #pragma unroll
    for (int i = 0; i < RF; i++)
        #pragma unroll
        for (int j = 0; j < 4; j++) acc[i][j] = (f32x4){0.f, 0.f, 0.f, 0.f};

    // per-instr global source base (per-lane) and uniform LDS dest
    const unsigned short* gA[nAi];
    #pragma unroll
    for (int i = 0; i < nAi; i++) {
        const int cl = (wave * nAi + i) * 64 + lane;
        gA[i] = A + (size_t)(m0 + (cl >> 2)) * K + (cl & 3) * 8;
    }
    const unsigned short* gB[2];
    #pragma unroll
    for (int i = 0; i < 2; i++) {
        const int cl = (wave * 2 + i) * 64 + lane;
        gB[i] = BT + (size_t)(n0 + (cl >> 2)) * K + (cl & 3) * 8;
    }

    for (int k0 = 0; k0 < K; k0 += 32) {
        __syncthreads();
        #pragma unroll
        for (int i = 0; i < nAi; i++)
            async_copy16(gA[i] + k0, &As[(wave * nAi + i) * 512]);
        #pragma unroll
        for (int i = 0; i < 2; i++)
            async_copy16(gB[i] + k0, &Bs[(wave * 2 + i) * 512]);
        __syncthreads();   // compiler drains vmcnt before barrier
        short8 af[RF], bfr[4];
        #pragma unroll
        for (int i = 0; i < RF; i++)
            af[i] = *(const short8*)&As[(wr + i * 16 + lr) * 32 + 8 * lg];
        #pragma unroll
        for (int j = 0; j < 4; j++)
            bfr[j] = *(const short8*)&Bs[(wc + j * 16 + lr) * 32 + 8 * lg];
        #pragma unroll
        for (int i = 0; i < RF; i++)
            #pragma unroll
            for (int j = 0; j < 4; j++)
                acc[i][j] = MFMA16(af[i], bfr[j], acc[i][j]);
    }

    // Epilogue. D layout: row = (lane>>4)*4 + reg, col = lane&15.
    #pragma unroll
    for (int i = 0; i < RF; i++) {
        #pragma unroll
        for (int j = 0; j < 4; j++) {
            const int rb = m0 + wr + i * 16 + lg * 4;
            const int c  = n0 + wc + j * 16 + lr;
            if constexpr (EPI == EP_QKV) {
                if (c < 2048) {        // Q -> q_raw [S][2048]
                    #pragma unroll
                    for (int r = 0; r < 4; r++)
                        ((unsigned short*)outp)[(size_t)(rb + r) * 2048 + c] =
                            f2b_bits(acc[i][j][r]);
                } else if (c < 3072) { // K -> k_raw [S][1024]
                    #pragma unroll
                    for (int r = 0; r < 4; r++)
                        ((unsigned short*)outp2)[(size_t)(rb + r) * 1024 + (c - 2048)] =
                            f2b_bits(acc[i][j][r]);
                } else {               // V -> vT [1024][S] (transposed)
                    u16x4 pk4;
                    #pragma unroll
                    for (int r = 0; r < 4; r++) pk4[r] = f2b_bits(acc[i][j][r]);
                    *(u16x4*)((unsigned short*)outp3 + (size_t)(c - 3072) * 2048 + rb) = pk4;
                }
            } else {
                #pragma unroll
                for (int r = 0; r < 4; r++) {
                    const int row = rb + r;
                    const size_t idx = (size_t)row * N + c;
                    const float v = acc[i][j][r];
                    if constexpr (EPI == EP_BF16) {
                        ((unsigned short*)outp)[idx] = f2b_bits(v);
                    } else if constexpr (EPI == EP_XGATE) {
                        ((float*)outp)[idx] = xin[idx] + modp[(row >> 8) * 6144 + 4096 + c] * v;
                    } else if constexpr (EPI == EP_SILUMUL) {
                        const float uu = b2f_bits(up[idx]);
                        ((unsigned short*)outp)[idx] = f2b_bits(silu_f(uu) * v);
                    } else {  // EP_ADDOUT
                        ((float*)outp)[idx] = ((float*)outp)[idx] + v;
                    }
                }
            }
        }
    }
}

// ---------------------------------------------------------------------------
// Flash attention, causal, GQA.  Round 3: LDS-staged KV shared by 4 waves.
// Block = (kvh, qt): 2 heads x 32 q-rows x 2 kv-split streams.
//   wave = hs*2 + ks:  head h = 2*kvh + hs;  ks-stream takes kv tiles j%2==ks.
// Superstep: stage kv-tiles 2ss, 2ss+1 (K 2x16KB + V^T 2x16KB, XOR-swizzled
// via pre-swizzled global source) -> barrier -> each wave computes its tile.
// End: kv-split partials combined via LDS.   Grid (8 kvh, 64 qt desc) = 512.
// 32x32x16 MFMA, swapped QK^T (lane-local softmax), verified pack/exchange.
// ---------------------------------------------------------------------------
__global__ __launch_bounds__(256, 2) void attn_kernel(
    const unsigned short* __restrict__ q,   // [S][2048] roped, pre-scaled
    const unsigned short* __restrict__ kk,  // [S][1024] roped
    const unsigned short* __restrict__ vT,  // [1024][S]
    unsigned short* __restrict__ o)         // [S][2048]
{
    __shared__ unsigned short Ks[2][8192];  // [tile][kv 64 x 128 shorts] 32KB
    __shared__ unsigned short Vs[2][8192];  // [tile][d 128 x 64 shorts]  32KB
    const int tid = threadIdx.x, wave = tid >> 6, lane = tid & 63;
    const int l5 = lane & 31, hi = lane >> 5;
    const int kvh = blockIdx.x;
    const int qt  = 63 - blockIdx.y;        // LPT: big blocks dispatch first
    const int hs = wave >> 1, ks = wave & 1;
    const int h = kvh * 2 + hs;
    const int q0 = qt * 32;
    const int qrow = q0 + l5;
    const int niter = (qt >> 1) + 1;        // 64-kv tiles needed
    const int nss = (niter + 1) >> 1;

    short8 qf[8];
    {
        const unsigned short* qp = q + (size_t)qrow * 2048 + h * 128 + hi * 8;
        #pragma unroll
        for (int kf = 0; kf < 8; kf++) qf[kf] = *(const short8*)(qp + kf * 16);
    }

    f32x16 ot[4];
    #pragma unroll
    for (int df = 0; df < 4; df++)
        #pragma unroll
        for (int r = 0; r < 16; r++) ot[df][r] = 0.0f;
    float m_ = -3e30f, l_ = 0.0f;

    for (int ss = 0; ss < nss; ss++) {
        const int kvA = ss * 128;
        // ---- cooperative stage: K tiles (4 rows x 256B per instr) ----
        #pragma unroll
        for (int t = 0; t < 2; t++) {
            #pragma unroll
            for (int i = 0; i < 4; i++) {
                const int cl = (wave * 4 + i) * 64 + lane;      // [0,1024)
                const int row = cl >> 4, c = cl & 15;           // K: 64r x 16c
                async_copy16(kk + (size_t)(kvA + t * 64 + row) * 1024 + kvh * 128
                                 + ((c ^ (row & 15)) * 8),
                             &Ks[t][(wave * 4 + i) * 512]);
            }
            #pragma unroll
            for (int i = 0; i < 4; i++) {
                const int cl = (wave * 4 + i) * 64 + lane;
                const int row = cl >> 3, c = cl & 7;            // V: 128r x 8c
                async_copy16(vT + (size_t)(kvh * 128 + row) * 2048 + kvA + t * 64
                                 + ((c ^ (row & 7)) * 8),
                             &Vs[t][(wave * 4 + i) * 512]);
            }
        }
        __syncthreads();

        const int j = 2 * ss + ks;
        if (j < niter) {
            const int kv0 = j * 64;
            // ---- QK^T (swapped) from swizzled LDS ----
            f32x16 st[2];
            #pragma unroll
            for (int nf = 0; nf < 2; nf++)
                #pragma unroll
                for (int r = 0; r < 16; r++) st[nf][r] = 0.0f;
            #pragma unroll
            for (int kf = 0; kf < 8; kf++) {
                const int ch = (kf * 2 + hi) ^ (l5 & 15);
                const short8 k0v = *(const short8*)&Ks[ks][l5 * 128 + ch * 8];
                const short8 k1v = *(const short8*)&Ks[ks][(l5 + 32) * 128 + ch * 8];
                st[0] = MFMA32(k0v, qf[kf], st[0]);
                st[1] = MFMA32(k1v, qf[kf], st[1]);
            }
            // ---- mask + online softmax (lane-local row) ----
            float sv[2][16];
            #pragma unroll
            for (int nf = 0; nf < 2; nf++)
                #pragma unroll
                for (int r = 0; r < 16; r++) {
                    const int kvi = kv0 + nf * 32 + (r & 3) + 8 * (r >> 2) + 4 * hi;
                    sv[nf][r] = (kvi > qrow) ? -3e30f : st[nf][r];
                }
            float pmax = sv[0][0];
            #pragma unroll
            for (int nf = 0; nf < 2; nf++)
                #pragma unroll
                for (int r = 0; r < 16; r++) pmax = fmaxf(pmax, sv[nf][r]);
            pmax = fmaxf(pmax, __shfl_xor(pmax, 32));
            const float mnew = fmaxf(m_, pmax);
            const float alpha = __expf(m_ - mnew);
            m_ = mnew;
            float rs = 0.0f;
            #pragma unroll
            for (int nf = 0; nf < 2; nf++)
                #pragma unroll
                for (int r = 0; r < 16; r++) {
                    const float p = __expf(sv[nf][r] - mnew);
                    sv[nf][r] = p;
                    rs += p;
                }
            rs += __shfl_xor(rs, 32);
            l_ = l_ * alpha + rs;
            #pragma unroll
            for (int df = 0; df < 4; df++)
                #pragma unroll
                for (int r = 0; r < 16; r++) ot[df][r] *= alpha;
            // ---- pack P to bf16 + cross-half exchange -> PV B-frags ----
            short8 pa[4];
            #pragma unroll
            for (int nf = 0; nf < 2; nf++) {
                #pragma unroll
                for (int hh = 0; hh < 2; hh++) {
                    unsigned int a0 = ((unsigned int)f2b_bits(sv[nf][8 * hh + 1]) << 16) | f2b_bits(sv[nf][8 * hh + 0]);
                    unsigned int a1 = ((unsigned int)f2b_bits(sv[nf][8 * hh + 3]) << 16) | f2b_bits(sv[nf][8 * hh + 2]);
                    unsigned int a2 = ((unsigned int)f2b_bits(sv[nf][8 * hh + 5]) << 16) | f2b_bits(sv[nf][8 * hh + 4]);
                    unsigned int a3 = ((unsigned int)f2b_bits(sv[nf][8 * hh + 7]) << 16) | f2b_bits(sv[nf][8 * hh + 6]);
                    const unsigned int x0 = (unsigned int)__shfl_xor((int)a0, 32);
                    const unsigned int x1 = (unsigned int)__shfl_xor((int)a1, 32);
                    const unsigned int x2 = (unsigned int)__shfl_xor((int)a2, 32);
                    const unsigned int x3 = (unsigned int)__shfl_xor((int)a3, 32);
                    union { unsigned int u[4]; short8 s; } cv;
                    cv.u[0] = hi ? x2 : a0;
                    cv.u[1] = hi ? x3 : a1;
                    cv.u[2] = hi ? a2 : x0;
                    cv.u[3] = hi ? a3 : x1;
                    pa[nf * 2 + hh] = cv.s;
                }
            }
            // ---- PV (swapped) from swizzled LDS ----
            #pragma unroll
            for (int df = 0; df < 4; df++) {
                const int d = df * 32 + l5;
                #pragma unroll
                for (int kvf = 0; kvf < 4; kvf++) {
                    const int ch = (kvf * 2 + hi) ^ (d & 7);
                    const short8 vfrag = *(const short8*)&Vs[ks][d * 64 + ch * 8];
                    ot[df] = MFMA32(vfrag, pa[kvf], ot[df]);
                }
            }
        }
        __syncthreads();
    }

    // ---- kv-split combine (reuse Ks as f32 scratch) ----
    float* Osh = (float*)&Ks[0][0];          // [2 heads][128 d][32 q] f32 = 32KB
    float* msh = (float*)&Vs[0][0];          // [2 heads][m(32) | l(32)]
    if (ks == 1) {
        #pragma unroll
        for (int df = 0; df < 4; df++)
            #pragma unroll
            for (int r = 0; r < 16; r++) {
                const int d = df * 32 + (r & 3) + 8 * (r >> 2) + 4 * hi;
                Osh[hs * 4096 + d * 32 + l5] = ot[df][r];
            }
        if (hi == 0) { msh[hs * 64 + l5] = m_; msh[hs * 64 + 32 + l5] = l_; }
    }
    __syncthreads();
    if (ks == 0) {
        const float m1 = msh[hs * 64 + l5], l1 = msh[hs * 64 + 32 + l5];
        const float mF = fmaxf(m_, m1);
        const float a0 = __expf(m_ - mF), a1 = __expf(m1 - mF);
        const float rinv = 1.0f / (l_ * a0 + l1 * a1);
        #pragma unroll
        for (int df = 0; df < 4; df++) {
            #pragma unroll
            for (int g = 0; g < 4; g++) {        // 4 consecutive d per group
                u16x4 pk;
                #pragma unroll
                for (int e = 0; e < 4; e++) {
                    const int d = df * 32 + e + 8 * g + 4 * hi;
                    const float ov = ot[df][4 * g + e] * a0 + Osh[hs * 4096 + d * 32 + l5] * a1;
                    pk[e] = f2b_bits(ov * rinv);
                }
                *(u16x4*)(o + (size_t)qrow * 2048 + h * 128 + df * 32 + 8 * g + 4 * hi) = pk;
            }
        }
    }
}

// ---------------------------------------------------------------------------
extern "C" void kernel_launch(void* const* d_in, const int* in_sizes, int n_in,
                              void* d_out, int out_size, void* d_ws, size_t ws_size,
                              hipStream_t stream) {
    (void)in_sizes; (void)n_in; (void)out_size; (void)ws_size;
    const float* x     = (const float*)d_in[0];
    const float* vec   = (const float*)d_in[1];
    const float* cosb  = (const float*)d_in[2];
    const float* sinb  = (const float*)d_in[3];
    // d_in[4] = mask: causal, reproduced analytically
    const float* wq    = (const float*)d_in[5];
    const float* wk    = (const float*)d_in[6];
    const float* wv    = (const float*)d_in[7];
    const float* wo    = (const float*)d_in[8];
    const float* w1    = (const float*)d_in[9];
    const float* w2    = (const float*)d_in[10];
    const float* w3    = (const float*)d_in[11];
    const float* mod_w = (const float*)d_in[12];
    const float* mod_b = (const float*)d_in[13];
    const float* anw   = (const float*)d_in[14];
    const float* fnw   = (const float*)d_in[15];
    float* out = (float*)d_out;

    char* ws = (char*)d_ws;
    size_t off = 0;
    auto alloc = [&](size_t bytes) -> void* {
        void* p = ws + off; off += (bytes + 255) & ~(size_t)255; return p;
    };
    unsigned short* WTqkv = (unsigned short*)alloc((size_t)4096 * 2048 * 2); // [wq;wk;wv]
    unsigned short* WTo   = (unsigned short*)alloc((size_t)2048 * 2048 * 2);
    unsigned short* WT1   = (unsigned short*)alloc((size_t)5632 * 2048 * 2);
    unsigned short* WT3   = (unsigned short*)alloc((size_t)5632 * 2048 * 2);
    unsigned short* WT2   = (unsigned short*)alloc((size_t)2048 * 5632 * 2);
    float* svec = (float*)alloc((size_t)8 * 2048 * 4);
    float* part = (float*)alloc((size_t)64 * 6144 * 4);
    float* modb = (float*)alloc((size_t)8 * 6144 * 4);
    unsigned short* h    = (unsigned short*)alloc((size_t)2048 * 2048 * 2);  // also hn
    unsigned short* qb   = (unsigned short*)alloc((size_t)2048 * 2048 * 2);
    unsigned short* kb   = (unsigned short*)alloc((size_t)2048 * 1024 * 2);
    unsigned short* vT   = (unsigned short*)alloc((size_t)1024 * 2048 * 2);
    unsigned short* ob   = (unsigned short*)alloc((size_t)2048 * 2048 * 2);
    unsigned short* u    = (unsigned short*)alloc((size_t)2048 * 5632 * 2);
    unsigned short* ffin = (unsigned short*)alloc((size_t)2048 * 5632 * 2);
    unsigned short* q_raw = u;     // lifetime-disjoint alias
    unsigned short* k_raw = ffin;  // lifetime-disjoint alias

    const float qscale = 0.08838834764831845f;  // 1/sqrt(128) folded into Wq

    // Weights -> bf16 transposed (Q|K|V fused into one [4096][2048] matrix)
    transpose_kernel<<<dim3(32, 32), 256, 0, stream>>>(wq, WTqkv, 2048, 2048, qscale);
    transpose_kernel<<<dim3(16, 32), 256, 0, stream>>>(wk, WTqkv + (size_t)2048 * 2048, 2048, 1024, 1.0f);
    transpose_kernel<<<dim3(16, 32), 256, 0, stream>>>(wv, WTqkv + (size_t)3072 * 2048, 2048, 1024, 1.0f);
    transpose_kernel<<<dim3(32, 32), 256, 0, stream>>>(wo, WTo, 2048, 2048, 1.0f);
    transpose_kernel<<<dim3(88, 32), 256, 0, stream>>>(w1, WT1, 2048, 5632, 1.0f);
    transpose_kernel<<<dim3(88, 32), 256, 0, stream>>>(w3, WT3, 2048, 5632, 1.0f);
    transpose_kernel<<<dim3(32, 88), 256, 0, stream>>>(w2, WT2, 5632, 2048, 1.0f);

    // Modulation
    silu_kernel<<<64, 256, 0, stream>>>(vec, svec, 8 * 2048);
    mod_gemm1<<<dim3(24, 8), 256, 0, stream>>>(svec, mod_w, part);
    mod_gemm2<<<192, 256, 0, stream>>>(part, mod_b, modb);

    // h = (1+scale)*rmsnorm(x)*anw + shift   (bf16)
    norm_kernel<true><<<2048, 256, 0, stream>>>(x, anw, modb, h);

    // Fused QKV GEMM (N=4096, 512 blocks)
    gemm_kernel<4, EP_QKV><<<dim3(32, 16), 256, 0, stream>>>(
        h, WTqkv, q_raw, k_raw, vT, nullptr, nullptr, nullptr, 2048, 4096, 2048);

    // RoPE
    rope_kernel<16><<<8192, 256, 0, stream>>>(q_raw, qb, cosb, sinb);
    rope_kernel<8><<<4096, 256, 0, stream>>>(k_raw, kb, cosb, sinb);

    // Attention (kvh on blockIdx.x -> XCD-pinned KV; qt descending -> LPT)
    attn_kernel<<<dim3(8, 64), 256, 0, stream>>>(qb, kb, vT, ob);

    // x_mid = x + gate * (o @ wo)   -> d_out (f32)   (64-row tiles, 512 blocks)
    gemm_kernel<2, EP_XGATE><<<dim3(16, 32), 256, 0, stream>>>(
        ob, WTo, out, nullptr, nullptr, x, modb, nullptr, 2048, 2048, 2048);

    // hn = rmsnorm(x_mid)*fnw  (bf16, reuses h)
    norm_kernel<false><<<2048, 256, 0, stream>>>(out, fnw, nullptr, h);

    // FFN: u = hn@w1 ; ffin = silu(u)*(hn@w3) ; out += ffin@w2
    gemm_kernel<4, EP_BF16><<<dim3(44, 16), 256, 0, stream>>>(
        h, WT1, u, nullptr, nullptr, nullptr, nullptr, nullptr, 2048, 5632, 2048);
    gemm_kernel<4, EP_SILUMUL><<<dim3(44, 16), 256, 0, stream>>>(
        h, WT3, ffin, nullptr, nullptr, nullptr, nullptr, u, 2048, 5632, 2048);
    gemm_kernel<2, EP_ADDOUT><<<dim3(16, 32), 256, 0, stream>>>(
        ffin, WT2, out, nullptr, nullptr, nullptr, nullptr, nullptr, 2048, 2048, 5632);
}

// Round 4
// 460.248 us; speedup vs baseline: 2.1401x; 1.2339x over previous
//
#include <hip/hip_runtime.h>
#include <hip/hip_bf16.h>

// ---------------------------------------------------------------------------
// TokenFlowModel block on MI355X (gfx950).  Round 4.
// B=1, S=2048, D=2048, H=16, KVH=8, HD=128, FH=5632, M_=8, N_=256.
// GEMMs: 128x128 RF=4 tile, BK=32, DOUBLE-BUFFERED 2-phase (stage t+1 before
//   compute t, single barrier/step), XOR chunk-swizzled LDS (pre-swizzled
//   global source, linear gload_lds dest), XCD-aware block swizzle,
//   split-K x2 for the 256-block shapes (WO, W2), RoPE fused in QKV epilogue.
// Attention: unchanged from round 3 (LDS-staged KV shared by 4 waves).
// ---------------------------------------------------------------------------

typedef __attribute__((ext_vector_type(8))) short short8;   // 8 x bf16
typedef __attribute__((ext_vector_type(4))) float f32x4;
typedef __attribute__((ext_vector_type(16))) float f32x16;
typedef __attribute__((ext_vector_type(4))) unsigned short u16x4;

#define MFMA16(a, b, c) __builtin_amdgcn_mfma_f32_16x16x32_bf16((a), (b), (c), 0, 0, 0)
#define MFMA32(a, b, c) __builtin_amdgcn_mfma_f32_32x32x16_bf16((a), (b), (c), 0, 0, 0)

__device__ __forceinline__ unsigned short f2b_bits(float f) {
    union { float f; unsigned int u; } cv; cv.f = f;
    unsigned int u = cv.u;
    u += 0x7fffu + ((u >> 16) & 1u);   // round-to-nearest-even
    return (unsigned short)(u >> 16);
}
__device__ __forceinline__ float b2f_bits(unsigned short b) {
    union { float f; unsigned int u; } cv; cv.u = ((unsigned int)b) << 16; return cv.f;
}
__device__ __forceinline__ float silu_f(float x) { return x / (1.0f + __expf(-x)); }

// async global->LDS, 16B per lane.  LDS dest: wave-uniform base + lane*16.
__device__ __forceinline__ void async_copy16(const unsigned short* g, unsigned short* l) {
    __builtin_amdgcn_global_load_lds(
        (const __attribute__((address_space(1))) unsigned int*)g,
        (__attribute__((address_space(3))) unsigned int*)l, 16, 0, 0);
}

// ---------------------------------------------------------------------------
// Weight transpose + f32->bf16 (+ optional scale): W[K][N] -> WT[N][K] bf16
// ---------------------------------------------------------------------------
__global__ __launch_bounds__(256) void transpose_kernel(
    const float* __restrict__ W, unsigned short* __restrict__ WT, int K, int N,
    float scale)
{
    __shared__ float t[64][65];
    const int tid = threadIdx.x;
    const int k0 = blockIdx.y * 64, n0 = blockIdx.x * 64;
    {
        const int row = tid >> 2, cq = (tid & 3) * 16;
        const float* src = W + (size_t)(k0 + row) * N + n0 + cq;
        #pragma unroll
        for (int i = 0; i < 4; i++) {
            float4 v = *(const float4*)(src + i * 4);
            t[row][cq + i * 4 + 0] = v.x;
            t[row][cq + i * 4 + 1] = v.y;
            t[row][cq + i * 4 + 2] = v.z;
            t[row][cq + i * 4 + 3] = v.w;
        }
    }
    __syncthreads();
    {
        const int n = tid >> 2, kq = (tid & 3) * 16;
        short8 v0, v1;
        #pragma unroll
        for (int i = 0; i < 8; i++) {
            v0[i] = (short)f2b_bits(t[kq + i][n] * scale);
            v1[i] = (short)f2b_bits(t[kq + 8 + i][n] * scale);
        }
        unsigned short* dst = WT + (size_t)(n0 + n) * K + k0 + kq;
        *(short8*)(dst) = v0;
        *(short8*)(dst + 8) = v1;
    }
}

// ---------------------------------------------------------------------------
// silu(vec) -> svec   (8 x 2048)
// ---------------------------------------------------------------------------
__global__ void silu_kernel(const float* __restrict__ in, float* __restrict__ outp, int n) {
    int i = blockIdx.x * 256 + threadIdx.x;
    if (i < n) outp[i] = silu_f(in[i]);
}

// ---------------------------------------------------------------------------
// mod GEMM pass 1: part[kc][m][6144] partial sums (mod_w read exactly once)
// ---------------------------------------------------------------------------
__global__ __launch_bounds__(256) void mod_gemm1(
    const float* __restrict__ svec, const float* __restrict__ mw,
    float* __restrict__ part)
{
    __shared__ float svs[8][256];
    const int tid = threadIdx.x;
    const int nb = blockIdx.x, kc = blockIdx.y;
    const int n = nb * 256 + tid;
    #pragma unroll
    for (int m8 = 0; m8 < 8; m8++) svs[m8][tid] = svec[m8 * 2048 + kc * 256 + tid];
    __syncthreads();
    float acc[8];
    #pragma unroll
    for (int m = 0; m < 8; m++) acc[m] = 0.0f;
    for (int k = 0; k < 256; k++) {
        const float w = mw[(size_t)(kc * 256 + k) * 6144 + n];
        #pragma unroll
        for (int m = 0; m < 8; m++) acc[m] += svs[m][k] * w;
    }
    #pragma unroll
    for (int m = 0; m < 8; m++) part[(size_t)(kc * 8 + m) * 6144 + n] = acc[m];
}

// pass 2: modb[m][6144] = sum_kc part + mb  (fixed order -> deterministic)
__global__ void mod_gemm2(const float* __restrict__ part, const float* __restrict__ mb,
                          float* __restrict__ modb)
{
    const int i = blockIdx.x * 256 + threadIdx.x;   // 8*6144
    const int n = i % 6144;
    float a = mb[n];
    #pragma unroll
    for (int kc = 0; kc < 8; kc++) a += part[(size_t)(kc * 8 + (i / 6144)) * 6144 + n];
    modb[i] = a;
}

// ---------------------------------------------------------------------------
// RMSNorm (+ optional AdaLN modulation) -> bf16 row.  One block per row.
// ---------------------------------------------------------------------------
template<bool MOD>
__global__ __launch_bounds__(256) void norm_kernel(
    const float* __restrict__ xin, const float* __restrict__ w,
    const float* __restrict__ mod, unsigned short* __restrict__ outp)
{
    const int s = blockIdx.x, tid = threadIdx.x;
    const float* xr = xin + (size_t)s * 2048;
    float4 a4 = *(const float4*)(xr + tid * 8);
    float4 b4 = *(const float4*)(xr + tid * 8 + 4);
    float v[8] = {a4.x, a4.y, a4.z, a4.w, b4.x, b4.y, b4.z, b4.w};
    float ss = 0.0f;
    #pragma unroll
    for (int i = 0; i < 8; i++) ss += v[i] * v[i];
    #pragma unroll
    for (int off = 1; off < 64; off <<= 1) ss += __shfl_xor(ss, off);
    __shared__ float red[4];
    if ((tid & 63) == 0) red[tid >> 6] = ss;
    __syncthreads();
    ss = red[0] + red[1] + red[2] + red[3];
    const float inv = rsqrtf(ss * (1.0f / 2048.0f) + 1e-6f);
    const int g = s >> 8;
    #pragma unroll
    for (int i = 0; i < 8; i++) {
        const int d = tid * 8 + i;
        float y = v[i] * inv * w[d];
        if (MOD) y = y * (1.0f + mod[g * 6144 + 2048 + d]) + mod[g * 6144 + d];
        outp[(size_t)s * 2048 + d] = f2b_bits(y);
    }
}

// ---------------------------------------------------------------------------
// bf16 GEMM, 2-phase double-buffered: C[M][N] = A[M][K] @ BT[N][K]^T.
// 128x128 tile, BK=32, gload_lds width-16, XOR chunk swizzle (c ^= (r>>1)&3),
// XCD block swizzle.  Split-K via blockIdx.z (kspl = K length per z).
// ---------------------------------------------------------------------------
enum { EP_QKV = 0, EP_BF16 = 1, EP_SILUMUL = 2, EP_PART = 3 };

template<int EPI>
__global__ __launch_bounds__(256, 2) void gemm_kernel(
    const unsigned short* __restrict__ A, const unsigned short* __restrict__ BT,
    void* __restrict__ outp, void* __restrict__ outp2, void* __restrict__ outp3,
    const unsigned short* __restrict__ up,  // EP_SILUMUL: u = hn@w1 (bf16)
    const float* __restrict__ ct, const float* __restrict__ st,  // EP_QKV rope
    int M, int N, int K, int kspl)
{
    __shared__ unsigned short As[8192];   // 2 bufs x 128 x 32
    __shared__ unsigned short Bs[8192];
    const int tid = threadIdx.x;
    const int lane = tid & 63, wave = tid >> 6;

    // XCD-aware bijective block swizzle (nwg % 8 == 0 for all our grids)
    const int nwg = gridDim.x * gridDim.y;
    const int fid = blockIdx.y * gridDim.x + blockIdx.x;
    const int sid = (fid & 7) * (nwg >> 3) + (fid >> 3);
    const int m0 = (sid / gridDim.x) * 128;
    const int n0 = (sid % gridDim.x) * 128;
    const int kb0 = blockIdx.z * kspl;

    const int wr = (wave >> 1) * 64, wc = (wave & 1) * 64;
    const int lr = lane & 15, lg = lane >> 4;
    const int rcol = (lg ^ ((lr >> 1) & 3)) * 8;   // swizzled read chunk

    // staging sources (pre-swizzled chunk within each 64B row)
    const int cl0 = (wave * 2 + 0) * 64 + lane;
    const int cl1 = (wave * 2 + 1) * 64 + lane;
    const int r0 = cl0 >> 2, c0 = cl0 & 3;
    const int r1 = cl1 >> 2, c1 = cl1 & 3;
    const unsigned short* gA0 = A + (size_t)(m0 + r0) * K + kb0 + (c0 ^ ((r0 >> 1) & 3)) * 8;
    const unsigned short* gA1 = A + (size_t)(m0 + r1) * K + kb0 + (c1 ^ ((r1 >> 1) & 3)) * 8;
    const unsigned short* gB0 = BT + (size_t)(n0 + r0) * K + kb0 + (c0 ^ ((r0 >> 1) & 3)) * 8;
    const unsigned short* gB1 = BT + (size_t)(n0 + r1) * K + kb0 + (c1 ^ ((r1 >> 1) & 3)) * 8;

    f32x4 acc[4][4];
    #pragma unroll
    for (int i = 0; i < 4; i++)
        #pragma unroll
        for (int j = 0; j < 4; j++) acc[i][j] = (f32x4){0.f, 0.f, 0.f, 0.f};

    const int nsteps = kspl >> 5;   // always even here

    auto stage = [&](int buf, int kofs) {
        unsigned short* la = As + buf * 4096 + wave * 1024;
        unsigned short* lb = Bs + buf * 4096 + wave * 1024;
        async_copy16(gA0 + kofs, la);
        async_copy16(gA1 + kofs, la + 512);
        async_copy16(gB0 + kofs, lb);
        async_copy16(gB1 + kofs, lb + 512);
    };
    auto dostep = [&](int t, int cur) {
        if (t + 1 < nsteps) stage(cur ^ 1, (t + 1) * 32);
        const unsigned short* ab = As + cur * 4096;
        const unsigned short* bb = Bs + cur * 4096;
        short8 af[4], bfr[4];
        #pragma unroll
        for (int i = 0; i < 4; i++)
            af[i] = *(const short8*)&ab[(wr + i * 16 + lr) * 32 + rcol];
        #pragma unroll
        for (int j = 0; j < 4; j++)
            bfr[j] = *(const short8*)&bb[(wc + j * 16 + lr) * 32 + rcol];
        #pragma unroll
        for (int i = 0; i < 4; i++)
            #pragma unroll
            for (int j = 0; j < 4; j++)
                acc[i][j] = MFMA16(af[i], bfr[j], acc[i][j]);
        __syncthreads();   // drains own stage vmcnt + all ds_reads
    };

    stage(0, 0);
    __syncthreads();
    for (int t = 0; t < nsteps; t += 2) { dostep(t, 0); dostep(t + 1, 1); }

    // Epilogue.  D layout: row = (lane>>4)*4 + reg, col = lane&15.
    #pragma unroll
    for (int i = 0; i < 4; i++) {
        #pragma unroll
        for (int j = 0; j < 4; j++) {
            const int rb = m0 + wr + i * 16 + lg * 4;
            const int c  = n0 + wc + j * 16 + lr;
            if constexpr (EPI == EP_QKV) {
                if (n0 < 3072) {        // Q or K: fused RoPE
                    const int crel = (n0 < 2048) ? c : (c - 2048);
                    const int dd = crel & 127;
                    const int pr = dd >> 1;
                    #pragma unroll
                    for (int r = 0; r < 4; r++) {
                        const float v = acc[i][j][r];
                        const float p = __shfl_xor(v, 1);
                        const float cs = ct[(rb + r) * 64 + pr];
                        const float sn = st[(rb + r) * 64 + pr];
                        const float res = (dd & 1) ? (p * sn + v * cs) : (v * cs - p * sn);
                        if (n0 < 2048)
                            ((unsigned short*)outp)[(size_t)(rb + r) * 2048 + crel] = f2b_bits(res);
                        else
                            ((unsigned short*)outp2)[(size_t)(rb + r) * 1024 + crel] = f2b_bits(res);
                    }
                } else {                // V -> vT [1024][S] (transposed)
                    u16x4 pk4;
                    #pragma unroll
                    for (int r = 0; r < 4; r++) pk4[r] = f2b_bits(acc[i][j][r]);
                    *(u16x4*)((unsigned short*)outp3 + (size_t)(c - 3072) * 2048 + rb) = pk4;
                }
            } else if constexpr (EPI == EP_PART) {
                float* pout = (float*)outp + (size_t)blockIdx.z * M * N;
                #pragma unroll
                for (int r = 0; r < 4; r++)
                    pout[(size_t)(rb + r) * N + c] = acc[i][j][r];
            } else {
                #pragma unroll
                for (int r = 0; r < 4; r++) {
                    const size_t idx = (size_t)(rb + r) * N + c;
                    if constexpr (EPI == EP_BF16) {
                        ((unsigned short*)outp)[idx] = f2b_bits(acc[i][j][r]);
                    } else {  // EP_SILUMUL
                        const float uu = b2f_bits(up[idx]);
                        ((unsigned short*)outp)[idx] = f2b_bits(silu_f(uu) * acc[i][j][r]);
                    }
                }
            }
        }
    }
}

// ---------------------------------------------------------------------------
// split-K combines (deterministic fixed-order sums)
// ---------------------------------------------------------------------------
__global__ void combine_xgate(const float* __restrict__ p, const float* __restrict__ x,
                              const float* __restrict__ modp, float* __restrict__ out)
{
    const size_t i = ((size_t)blockIdx.x * 256 + threadIdx.x) * 4;
    const int row = (int)(i >> 11), col = (int)(i & 2047);
    const float4 a = *(const float4*)(p + i);
    const float4 b = *(const float4*)(p + (size_t)2048 * 2048 + i);
    const float4 xv = *(const float4*)(x + i);
    const float4 g = *(const float4*)(modp + (row >> 8) * 6144 + 4096 + col);
    float4 o;
    o.x = xv.x + g.x * (a.x + b.x);
    o.y = xv.y + g.y * (a.y + b.y);
    o.z = xv.z + g.z * (a.z + b.z);
    o.w = xv.w + g.w * (a.w + b.w);
    *(float4*)(out + i) = o;
}

__global__ void combine_w2(const float* __restrict__ p, float* __restrict__ out)
{
    const size_t i = ((size_t)blockIdx.x * 256 + threadIdx.x) * 4;
    const float4 a = *(const float4*)(p + i);
    const float4 b = *(const float4*)(p + (size_t)2048 * 2048 + i);
    float4 o = *(const float4*)(out + i);
    o.x += a.x + b.x; o.y += a.y + b.y; o.z += a.z + b.z; o.w += a.w + b.w;
    *(float4*)(out + i) = o;
}

// ---------------------------------------------------------------------------
// Flash attention, causal, GQA.  (unchanged from round 3)
// ---------------------------------------------------------------------------
__global__ __launch_bounds__(256, 2) void attn_kernel(
    const unsigned short* __restrict__ q,   // [S][2048] roped, pre-scaled
    const unsigned short* __restrict__ kk,  // [S][1024] roped
    const unsigned short* __restrict__ vT,  // [1024][S]
    unsigned short* __restrict__ o)         // [S][2048]
{
    __shared__ unsigned short Ks[2][8192];  // [tile][kv 64 x 128 shorts] 32KB
    __shared__ unsigned short Vs[2][8192];  // [tile][d 128 x 64 shorts]  32KB
    const int tid = threadIdx.x, wave = tid >> 6, lane = tid & 63;
    const int l5 = lane & 31, hi = lane >> 5;
    const int kvh = blockIdx.x;
    const int qt  = 63 - blockIdx.y;        // LPT: big blocks dispatch first
    const int hs = wave >> 1, ks = wave & 1;
    const int h = kvh * 2 + hs;
    const int q0 = qt * 32;
    const int qrow = q0 + l5;
    const int niter = (qt >> 1) + 1;        // 64-kv tiles needed
    const int nss = (niter + 1) >> 1;

    short8 qf[8];
    {
        const unsigned short* qp = q + (size_t)qrow * 2048 + h * 128 + hi * 8;
        #pragma unroll
        for (int kf = 0; kf < 8; kf++) qf[kf] = *(const short8*)(qp + kf * 16);
    }

    f32x16 ot[4];
    #pragma unroll
    for (int df = 0; df < 4; df++)
        #pragma unroll
        for (int r = 0; r < 16; r++) ot[df][r] = 0.0f;
    float m_ = -3e30f, l_ = 0.0f;

    for (int ss = 0; ss < nss; ss++) {
        const int kvA = ss * 128;
        #pragma unroll
        for (int t = 0; t < 2; t++) {
            #pragma unroll
            for (int i = 0; i < 4; i++) {
                const int cl = (wave * 4 + i) * 64 + lane;      // [0,1024)
                const int row = cl >> 4, c = cl & 15;           // K: 64r x 16c
                async_copy16(kk + (size_t)(kvA + t * 64 + row) * 1024 + kvh * 128
                                 + ((c ^ (row & 15)) * 8),
                             &Ks[t][(wave * 4 + i) * 512]);
            }
            #pragma unroll
            for (int i = 0; i < 4; i++) {
                const int cl = (wave * 4 + i) * 64 + lane;
                const int row = cl >> 3, c = cl & 7;            // V: 128r x 8c
                async_copy16(vT + (size_t)(kvh * 128 + row) * 2048 + kvA + t * 64
                                 + ((c ^ (row & 7)) * 8),
                             &Vs[t][(wave * 4 + i) * 512]);
            }
        }
        __syncthreads();

        const int j = 2 * ss + ks;
        if (j < niter) {
            const int kv0 = j * 64;
            f32x16 st_[2];
            #pragma unroll
            for (int nf = 0; nf < 2; nf++)
                #pragma unroll
                for (int r = 0; r < 16; r++) st_[nf][r] = 0.0f;
            #pragma unroll
            for (int kf = 0; kf < 8; kf++) {
                const int ch = (kf * 2 + hi) ^ (l5 & 15);
                const short8 k0v = *(const short8*)&Ks[ks][l5 * 128 + ch * 8];
                const short8 k1v = *(const short8*)&Ks[ks][(l5 + 32) * 128 + ch * 8];
                st_[0] = MFMA32(k0v, qf[kf], st_[0]);
                st_[1] = MFMA32(k1v, qf[kf], st_[1]);
            }
            float sv[2][16];
            #pragma unroll
            for (int nf = 0; nf < 2; nf++)
                #pragma unroll
                for (int r = 0; r < 16; r++) {
                    const int kvi = kv0 + nf * 32 + (r & 3) + 8 * (r >> 2) + 4 * hi;
                    sv[nf][r] = (kvi > qrow) ? -3e30f : st_[nf][r];
                }
            float pmax = sv[0][0];
            #pragma unroll
            for (int nf = 0; nf < 2; nf++)
                #pragma unroll
                for (int r = 0; r < 16; r++) pmax = fmaxf(pmax, sv[nf][r]);
            pmax = fmaxf(pmax, __shfl_xor(pmax, 32));
            const float mnew = fmaxf(m_, pmax);
            const float alpha = __expf(m_ - mnew);
            m_ = mnew;
            float rs = 0.0f;
            #pragma unroll
            for (int nf = 0; nf < 2; nf++)
                #pragma unroll
                for (int r = 0; r < 16; r++) {
                    const float p = __expf(sv[nf][r] - mnew);
                    sv[nf][r] = p;
                    rs += p;
                }
            rs += __shfl_xor(rs, 32);
            l_ = l_ * alpha + rs;
            #pragma unroll
            for (int df = 0; df < 4; df++)
                #pragma unroll
                for (int r = 0; r < 16; r++) ot[df][r] *= alpha;
            short8 pa[4];
            #pragma unroll
            for (int nf = 0; nf < 2; nf++) {
                #pragma unroll
                for (int hh = 0; hh < 2; hh++) {
                    unsigned int a0 = ((unsigned int)f2b_bits(sv[nf][8 * hh + 1]) << 16) | f2b_bits(sv[nf][8 * hh + 0]);
                    unsigned int a1 = ((unsigned int)f2b_bits(sv[nf][8 * hh + 3]) << 16) | f2b_bits(sv[nf][8 * hh + 2]);
                    unsigned int a2 = ((unsigned int)f2b_bits(sv[nf][8 * hh + 5]) << 16) | f2b_bits(sv[nf][8 * hh + 4]);
                    unsigned int a3 = ((unsigned int)f2b_bits(sv[nf][8 * hh + 7]) << 16) | f2b_bits(sv[nf][8 * hh + 6]);
                    const unsigned int x0 = (unsigned int)__shfl_xor((int)a0, 32);
                    const unsigned int x1 = (unsigned int)__shfl_xor((int)a1, 32);
                    const unsigned int x2 = (unsigned int)__shfl_xor((int)a2, 32);
                    const unsigned int x3 = (unsigned int)__shfl_xor((int)a3, 32);
                    union { unsigned int u[4]; short8 s; } cv;
                    cv.u[0] = hi ? x2 : a0;
                    cv.u[1] = hi ? x3 : a1;
                    cv.u[2] = hi ? a2 : x0;
                    cv.u[3] = hi ? a3 : x1;
                    pa[nf * 2 + hh] = cv.s;
                }
            }
            #pragma unroll
            for (int df = 0; df < 4; df++) {
                const int d = df * 32 + l5;
                #pragma unroll
                for (int kvf = 0; kvf < 4; kvf++) {
                    const int ch = (kvf * 2 + hi) ^ (d & 7);
                    const short8 vfrag = *(const short8*)&Vs[ks][d * 64 + ch * 8];
                    ot[df] = MFMA32(vfrag, pa[kvf], ot[df]);
                }
            }
        }
        __syncthreads();
    }

    float* Osh = (float*)&Ks[0][0];          // [2 heads][128 d][32 q] f32 = 32KB
    float* msh = (float*)&Vs[0][0];          // [2 heads][m(32) | l(32)]
    if (ks == 1) {
        #pragma unroll
        for (int df = 0; df < 4; df++)
            #pragma unroll
            for (int r = 0; r < 16; r++) {
                const int d = df * 32 + (r & 3) + 8 * (r >> 2) + 4 * hi;
                Osh[hs * 4096 + d * 32 + l5] = ot[df][r];
            }
        if (hi == 0) { msh[hs * 64 + l5] = m_; msh[hs * 64 + 32 + l5] = l_; }
    }
    __syncthreads();
    if (ks == 0) {
        const float m1 = msh[hs * 64 + l5], l1 = msh[hs * 64 + 32 + l5];
        const float mF = fmaxf(m_, m1);
        const float a0 = __expf(m_ - mF), a1 = __expf(m1 - mF);
        const float rinv = 1.0f / (l_ * a0 + l1 * a1);
        #pragma unroll
        for (int df = 0; df < 4; df++) {
            #pragma unroll
            for (int g = 0; g < 4; g++) {
                u16x4 pk;
                #pragma unroll
                for (int e = 0; e < 4; e++) {
                    const int d = df * 32 + e + 8 * g + 4 * hi;
                    const float ov = ot[df][4 * g + e] * a0 + Osh[hs * 4096 + d * 32 + l5] * a1;
                    pk[e] = f2b_bits(ov * rinv);
                }
                *(u16x4*)(o + (size_t)qrow * 2048 + h * 128 + df * 32 + 8 * g + 4 * hi) = pk;
            }
        }
    }
}

// ---------------------------------------------------------------------------
extern "C" void kernel_launch(void* const* d_in, const int* in_sizes, int n_in,
                              void* d_out, int out_size, void* d_ws, size_t ws_size,
                              hipStream_t stream) {
    (void)in_sizes; (void)n_in; (void)out_size; (void)ws_size;
    const float* x     = (const float*)d_in[0];
    const float* vec   = (const float*)d_in[1];
    const float* cosb  = (const float*)d_in[2];
    const float* sinb  = (const float*)d_in[3];
    // d_in[4] = mask: causal, reproduced analytically
    const float* wq    = (const float*)d_in[5];
    const float* wk    = (const float*)d_in[6];
    const float* wv    = (const float*)d_in[7];
    const float* wo    = (const float*)d_in[8];
    const float* w1    = (const float*)d_in[9];
    const float* w2    = (const float*)d_in[10];
    const float* w3    = (const float*)d_in[11];
    const float* mod_w = (const float*)d_in[12];
    const float* mod_b = (const float*)d_in[13];
    const float* anw   = (const float*)d_in[14];
    const float* fnw   = (const float*)d_in[15];
    float* out = (float*)d_out;

    char* ws = (char*)d_ws;
    size_t off = 0;
    auto alloc = [&](size_t bytes) -> void* {
        void* p = ws + off; off += (bytes + 255) & ~(size_t)255; return p;
    };
    unsigned short* WTqkv = (unsigned short*)alloc((size_t)4096 * 2048 * 2); // [wq;wk;wv]
    unsigned short* WTo   = (unsigned short*)alloc((size_t)2048 * 2048 * 2);
    unsigned short* WT1   = (unsigned short*)alloc((size_t)5632 * 2048 * 2);
    unsigned short* WT3   = (unsigned short*)alloc((size_t)5632 * 2048 * 2);
    unsigned short* WT2   = (unsigned short*)alloc((size_t)2048 * 5632 * 2);
    float* svec = (float*)alloc((size_t)8 * 2048 * 4);
    float* part = (float*)alloc((size_t)64 * 6144 * 4);
    float* modb = (float*)alloc((size_t)8 * 6144 * 4);
    unsigned short* h    = (unsigned short*)alloc((size_t)2048 * 2048 * 2);  // also hn
    unsigned short* qb   = (unsigned short*)alloc((size_t)2048 * 2048 * 2);
    unsigned short* kb   = (unsigned short*)alloc((size_t)2048 * 1024 * 2);
    unsigned short* vT   = (unsigned short*)alloc((size_t)1024 * 2048 * 2);
    unsigned short* ob   = (unsigned short*)alloc((size_t)2048 * 2048 * 2);
    unsigned short* u    = (unsigned short*)alloc((size_t)2048 * 5632 * 2);
    unsigned short* ffin = (unsigned short*)alloc((size_t)2048 * 5632 * 2);

    // split-K partial buffers (32MB each, reuse dead regions):
    //  - XGATE partials: u..ffin region (free until W1 writes u)
    //  - W2 partials: h..ob region (all dead after W1/W3/attn/XGATE consumed)
    float* pxg = (float*)u;
    float* pw2 = (float*)h;

    const float qscale = 0.08838834764831845f;  // 1/sqrt(128) folded into Wq

    // Weights -> bf16 transposed (Q|K|V fused into one [4096][2048] matrix)
    transpose_kernel<<<dim3(32, 32), 256, 0, stream>>>(wq, WTqkv, 2048, 2048, qscale);
    transpose_kernel<<<dim3(16, 32), 256, 0, stream>>>(wk, WTqkv + (size_t)2048 * 2048, 2048, 1024, 1.0f);
    transpose_kernel<<<dim3(16, 32), 256, 0, stream>>>(wv, WTqkv + (size_t)3072 * 2048, 2048, 1024, 1.0f);
    transpose_kernel<<<dim3(32, 32), 256, 0, stream>>>(wo, WTo, 2048, 2048, 1.0f);
    transpose_kernel<<<dim3(88, 32), 256, 0, stream>>>(w1, WT1, 2048, 5632, 1.0f);
    transpose_kernel<<<dim3(88, 32), 256, 0, stream>>>(w3, WT3, 2048, 5632, 1.0f);
    transpose_kernel<<<dim3(32, 88), 256, 0, stream>>>(w2, WT2, 5632, 2048, 1.0f);

    // Modulation
    silu_kernel<<<64, 256, 0, stream>>>(vec, svec, 8 * 2048);
    mod_gemm1<<<dim3(24, 8), 256, 0, stream>>>(svec, mod_w, part);
    mod_gemm2<<<192, 256, 0, stream>>>(part, mod_b, modb);

    // h = (1+scale)*rmsnorm(x)*anw + shift   (bf16)
    norm_kernel<true><<<2048, 256, 0, stream>>>(x, anw, modb, h);

    // Fused QKV GEMM (N=4096, 512 blocks) with fused RoPE epilogue
    gemm_kernel<EP_QKV><<<dim3(32, 16), 256, 0, stream>>>(
        h, WTqkv, qb, kb, vT, nullptr, cosb, sinb, 2048, 4096, 2048, 2048);

    // Attention (kvh on blockIdx.x -> XCD-pinned KV; qt descending -> LPT)
    attn_kernel<<<dim3(8, 64), 256, 0, stream>>>(qb, kb, vT, ob);

    // o @ wo, split-K x2 -> f32 partials; combine: out = x + gate*(p0+p1)
    gemm_kernel<EP_PART><<<dim3(16, 16, 2), 256, 0, stream>>>(
        ob, WTo, pxg, nullptr, nullptr, nullptr, nullptr, nullptr, 2048, 2048, 2048, 1024);
    combine_xgate<<<4096, 256, 0, stream>>>(pxg, x, modb, out);

    // hn = rmsnorm(x_mid)*fnw  (bf16, reuses h)
    norm_kernel<false><<<2048, 256, 0, stream>>>(out, fnw, nullptr, h);

    // FFN: u = hn@w1 ; ffin = silu(u)*(hn@w3)
    gemm_kernel<EP_BF16><<<dim3(44, 16), 256, 0, stream>>>(
        h, WT1, u, nullptr, nullptr, nullptr, nullptr, nullptr, 2048, 5632, 2048, 2048);
    gemm_kernel<EP_SILUMUL><<<dim3(44, 16), 256, 0, stream>>>(
        h, WT3, ffin, nullptr, nullptr, u, nullptr, nullptr, 2048, 5632, 2048, 2048);

    // out += ffin @ w2, split-K x2 (K=5632 -> 2x2816)
    gemm_kernel<EP_PART><<<dim3(16, 16, 2), 256, 0, stream>>>(
        ffin, WT2, pw2, nullptr, nullptr, nullptr, nullptr, nullptr, 2048, 2048, 5632, 2816);
    combine_w2<<<4096, 256, 0, stream>>>(pw2, out);
}